// Round 2
// baseline (4998.819 us; speedup 1.0000x reference)
//
#include <hip/hip_runtime.h>
#include <stdint.h>

// ---------------------------------------------------------------------------
// NanoGPT forward (L=6,H=6,C=384,T=256,V=65,B=256) on gfx950.
// Residual x in bf16; GEMMs bf16 MFMA (f32 accum); flash attention per (b,h).
// Workspace budget ~172 MB (chunked QKV/attn by 64 batches, MLP by 16384 rows).
// ---------------------------------------------------------------------------

typedef unsigned short u16;
typedef unsigned int   u32;
typedef __attribute__((ext_vector_type(8))) short bf16x8;   // 8 bf16 (4 VGPR)
typedef __attribute__((ext_vector_type(4))) float f32x4;    // MFMA accumulator

typedef const __attribute__((address_space(1))) void* gas_ptr;
typedef __attribute__((address_space(3))) void* lds_ptr;

__device__ __forceinline__ void gld_lds16(const void* g, void* l) {
    __builtin_amdgcn_global_load_lds((gas_ptr)g, (lds_ptr)l, 16, 0, 0);
}

__device__ __forceinline__ u16 f2bf(float f) {          // RNE f32->bf16
    u32 u = __builtin_bit_cast(u32, f);
    u = u + 0x7fffu + ((u >> 16) & 1u);
    return (u16)(u >> 16);
}
__device__ __forceinline__ float bf2f(u16 h) { return __builtin_bit_cast(float, (u32)h << 16); }
__device__ __forceinline__ float bflo(u32 u) { return __builtin_bit_cast(float, u << 16); }
__device__ __forceinline__ float bfhi(u32 u) { return __builtin_bit_cast(float, u & 0xffff0000u); }

__device__ __forceinline__ float dot8(uint4 a, uint4 b) {
    float s;
    s  = bflo(a.x)*bflo(b.x) + bfhi(a.x)*bfhi(b.x);
    s += bflo(a.y)*bflo(b.y) + bfhi(a.y)*bfhi(b.y);
    s += bflo(a.z)*bflo(b.z) + bfhi(a.z)*bfhi(b.z);
    s += bflo(a.w)*bflo(b.w) + bfhi(a.w)*bfhi(b.w);
    return s;
}

// ---------------------------------------------------------------------------
// Convert+transpose: src f32 [L][R][C] -> dst bf16, dst[l*dls + (dco+c)*R + r]
// (i.e. per layer a [C][R] transposed block placed at column-offset dco)
// ---------------------------------------------------------------------------
__global__ __launch_bounds__(256)
void convT_k(const float* __restrict__ src, u16* __restrict__ dst,
             int L, int R, int C, int dls, int dco)
{
    size_t total  = (size_t)L * R * C;
    size_t stride = (size_t)gridDim.x * 256;
    for (size_t i = (size_t)blockIdx.x * 256 + threadIdx.x; i < total; i += stride) {
        size_t rc  = (size_t)R * C;
        size_t l   = i / rc;
        size_t rem = i - l * rc;
        int r = (int)(rem / C);
        int c = (int)(rem - (size_t)r * C);
        dst[l * (size_t)dls + (size_t)(dco + c) * R + r] = f2bf(src[i]);
    }
}

// ---------------------------------------------------------------------------
// Embedding: x[row][c] = bf16(tok_emb[idx[row]][c] + pos_emb[row%256][c])
// grid*256 = 65536*48 (8-elem groups). Also zeroes the 32-entry loss buffer.
// ---------------------------------------------------------------------------
__global__ __launch_bounds__(256)
void embed_k(const int* __restrict__ idx, const float* __restrict__ tok,
             const float* __restrict__ pos, u16* __restrict__ x,
             float* __restrict__ lossbuf)
{
    if (blockIdx.x == 0 && threadIdx.x < 32) lossbuf[threadIdx.x] = 0.f;
    int gi  = blockIdx.x * 256 + threadIdx.x;
    int row = gi / 48;
    int cg  = gi - row * 48;
    int t   = row & 255;
    const float4* ta = (const float4*)(tok + (size_t)idx[row] * 384 + cg * 8);
    const float4* pa = (const float4*)(pos + (size_t)t * 384 + cg * 8);
    float4 a0 = ta[0], a1 = ta[1], p0 = pa[0], p1 = pa[1];
    u16 o[8] = { f2bf(a0.x+p0.x), f2bf(a0.y+p0.y), f2bf(a0.z+p0.z), f2bf(a0.w+p0.w),
                 f2bf(a1.x+p1.x), f2bf(a1.y+p1.y), f2bf(a1.z+p1.z), f2bf(a1.w+p1.w) };
    *(uint4*)(x + (size_t)row * 384 + cg * 8) = *(uint4*)o;
}

// ---------------------------------------------------------------------------
// LayerNorm over C=384 (bf16 in, bf16 out): one wave per row. grid = 65536/4
// ---------------------------------------------------------------------------
__global__ __launch_bounds__(256)
void ln_k(const u16* __restrict__ x, const float* __restrict__ gg,
          const float* __restrict__ bb, u16* __restrict__ out)
{
    const int lane = threadIdx.x & 63;
    const int w    = threadIdx.x >> 6;
    const size_t row = (size_t)blockIdx.x * 4 + w;
    const u32* xr = (const u32*)(x + row * 384);
    u32 d[3] = { xr[lane], xr[64 + lane], xr[128 + lane] };
    float v[6];
#pragma unroll
    for (int k = 0; k < 3; ++k) { v[2*k] = bflo(d[k]); v[2*k+1] = bfhi(d[k]); }
    float s = 0.f, sq = 0.f;
#pragma unroll
    for (int j = 0; j < 6; ++j) { s += v[j]; sq += v[j]*v[j]; }
#pragma unroll
    for (int m = 1; m < 64; m <<= 1) { s += __shfl_xor(s, m); sq += __shfl_xor(sq, m); }
    float mean = s * (1.f / 384.f);
    float var  = sq * (1.f / 384.f) - mean * mean;
    float rs   = rsqrtf(var + 1e-5f);
    u32* orow = (u32*)(out + row * 384);
#pragma unroll
    for (int k = 0; k < 3; ++k) {
        int c = k * 128 + 2 * lane;
        float o0 = (v[2*k]   - mean) * rs * gg[c]   + bb[c];
        float o1 = (v[2*k+1] - mean) * rs * gg[c+1] + bb[c+1];
        orow[k*64 + lane] = (u32)f2bf(o0) | ((u32)f2bf(o1) << 16);
    }
}

// ---------------------------------------------------------------------------
// GEMM: A[M,K] bf16 row-major x Bt[N,K] bf16 (pre-transposed) -> C [M,N] bf16
// 128x128 tile, BK=32, 4 waves (2x2 of 64x64), mfma 16x16x32 bf16.
// global_load_lds(16B) staging, double-buffered, XOR-swizzle via pre-swizzled
// global source (T21). EPI: 0 = store, 1 = bias+relu, 2 = residual rmw (+bias)
// ---------------------------------------------------------------------------
template<int EPI>
__global__ __launch_bounds__(256)
void gemm_bt(const u16* __restrict__ A, const u16* __restrict__ Bt,
             u16* __restrict__ C, const float* __restrict__ bias, int K, int N)
{
    __shared__ u16 As[2][128*32];
    __shared__ u16 Bs[2][128*32];
    const int tid = threadIdx.x;
    const int lane = tid & 63;
    const int w  = tid >> 6;
    const int wm = w >> 1, wn = w & 1;
    const int m0 = blockIdx.x * 128;
    const int n0 = blockIdx.y * 128;
    const int g   = lane >> 4;
    const int l15 = lane & 15;

    f32x4 acc[4][4] = {};
    const int nk = K >> 5;

    auto stage = [&](int buf, int t) {
        const int k0 = t << 5;
#pragma unroll
        for (int c = 0; c < 2; ++c) {
            int i   = c * 256 + tid;
            int row = i >> 2;                       // 0..127
            int seg = (i & 3) ^ (row & 3);          // pre-swizzled source
            gld_lds16(A  + (size_t)(m0 + row) * K + k0 + seg * 8,
                      (char*)(&As[buf][0]) + (c * 256 + w * 64) * 16);
            gld_lds16(Bt + (size_t)(n0 + row) * K + k0 + seg * 8,
                      (char*)(&Bs[buf][0]) + (c * 256 + w * 64) * 16);
        }
    };

    stage(0, 0);
    __syncthreads();
    int cur = 0;
    for (int t = 0; t < nk; ++t) {
        if (t + 1 < nk) stage(cur ^ 1, t + 1);
        const char* Ab = (const char*)&As[cur][0];
        const char* Bb = (const char*)&Bs[cur][0];
        bf16x8 af[4], bfv[4];
#pragma unroll
        for (int fm = 0; fm < 4; ++fm) {
            int row = wm*64 + fm*16 + l15;
            af[fm] = *(const bf16x8*)(Ab + row*64 + ((g ^ (row & 3)) * 16));
        }
#pragma unroll
        for (int fn = 0; fn < 4; ++fn) {
            int row = wn*64 + fn*16 + l15;
            bfv[fn] = *(const bf16x8*)(Bb + row*64 + ((g ^ (row & 3)) * 16));
        }
#pragma unroll
        for (int fm = 0; fm < 4; ++fm)
#pragma unroll
            for (int fn = 0; fn < 4; ++fn)
                acc[fm][fn] = __builtin_amdgcn_mfma_f32_16x16x32_bf16(
                    af[fm], bfv[fn], acc[fm][fn], 0, 0, 0);
        __syncthreads();
        cur ^= 1;
    }

    // epilogue: D row = base + (lane>>4)*4 + r, col = base + (lane&15)
#pragma unroll
    for (int fm = 0; fm < 4; ++fm) {
        int rowb = m0 + wm*64 + fm*16 + g*4;
#pragma unroll
        for (int fn = 0; fn < 4; ++fn) {
            int col = n0 + wn*64 + fn*16 + l15;
            float bv = (EPI == 0) ? 0.f : bias[col];
#pragma unroll
            for (int r = 0; r < 4; ++r) {
                size_t off = (size_t)(rowb + r) * N + col;
                float vv = acc[fm][fn][r];
                if (EPI == 0) {
                    C[off] = f2bf(vv);
                } else if (EPI == 1) {
                    vv += bv; vv = vv > 0.f ? vv : 0.f;
                    C[off] = f2bf(vv);
                } else {
                    C[off] = f2bf(bf2f(C[off]) + vv + bv);
                }
            }
        }
    }
}

// ---------------------------------------------------------------------------
// Flash attention, one block per (b_local, h). qkv interleaved [row][1152]
// (q|k|v each 384 = 6 heads x 64). 4 waves; wave w owns Q rows [64w, 64w+64).
// K [256][64], Vt [64][256], per-wave P [64][64] in LDS, XOR-swizzled
// (byte ^= (row&7)<<4). Online softmax, causal. O -> op rows [b*256+t][384].
// ---------------------------------------------------------------------------
__global__ __launch_bounds__(256)
void attn_k(const u16* __restrict__ qkv, u16* __restrict__ op)
{
    __shared__ u16 Ks[256*64];        // 32 KiB
    __shared__ u16 Vt[64*256];        // 32 KiB (transposed)
    __shared__ u16 Ps[4][64*64];      // 32 KiB (per-wave)
    const int tid  = threadIdx.x;
    const int lane = tid & 63;
    const int w    = tid >> 6;
    const int g    = lane >> 4;
    const int l15  = lane & 15;
    const int bh = blockIdx.x;
    const int b  = bh / 6, hh = bh - b * 6;
    const size_t baseQ = (size_t)b * 256 * 1152 + hh * 64;
    const size_t baseK = baseQ + 384;
    const size_t baseV = baseQ + 768;

    // stage K via global_load_lds, pre-swizzled source (8 slots/row of 16B)
#pragma unroll
    for (int cc = 0; cc < 8; ++cc) {
        int i    = cc * 256 + tid;            // 0..2047 chunks
        int row  = i >> 3;
        int slot = (i & 7) ^ (row & 7);
        gld_lds16(qkv + baseK + (size_t)row * 1152 + slot * 8,
                  (char*)Ks + (cc * 256 + w * 64) * 16);
    }
    // stage V transposed (scalar swizzled ds writes)
#pragma unroll
    for (int it = 0; it < 16; ++it) {
        int j    = it * 256 + tid;            // 0..4095 groups of 4 elems
        int trow = j >> 4;
        int d0   = (j & 15) * 4;
        uint2 val = *(const uint2*)(qkv + baseV + (size_t)trow * 1152 + d0);
        u16 e0 = (u16)(val.x & 0xffff), e1 = (u16)(val.x >> 16);
        u16 e2 = (u16)(val.y & 0xffff), e3 = (u16)(val.y >> 16);
        *(u16*)((char*)Vt + (d0+0)*512 + ((trow*2) ^ (((d0+0)&7) << 4))) = e0;
        *(u16*)((char*)Vt + (d0+1)*512 + ((trow*2) ^ (((d0+1)&7) << 4))) = e1;
        *(u16*)((char*)Vt + (d0+2)*512 + ((trow*2) ^ (((d0+2)&7) << 4))) = e2;
        *(u16*)((char*)Vt + (d0+3)*512 + ((trow*2) ^ (((d0+3)&7) << 4))) = e3;
    }
    __syncthreads();

    const int r0 = w * 64;
    bf16x8 qf[4][2];
#pragma unroll
    for (int fm = 0; fm < 4; ++fm)
#pragma unroll
        for (int kk = 0; kk < 2; ++kk)
            qf[fm][kk] = *(const bf16x8*)(qkv + baseQ +
                (size_t)(r0 + fm*16 + l15) * 1152 + kk*32 + g*8);

    f32x4 oacc[4][4] = {};
    float mst[4][4], lst[4][4];
#pragma unroll
    for (int i = 0; i < 4; ++i)
#pragma unroll
        for (int r = 0; r < 4; ++r) { mst[i][r] = -1e30f; lst[i][r] = 0.f; }

    for (int kt = 0; kt <= w; ++kt) {
        f32x4 s[4][4] = {};
#pragma unroll
        for (int kk = 0; kk < 2; ++kk) {
            bf16x8 kf[4];
#pragma unroll
            for (int fn = 0; fn < 4; ++fn) {
                int row = kt*64 + fn*16 + l15;
                kf[fn] = *(const bf16x8*)((char*)Ks + row*128 +
                          ((kk*64 + g*16) ^ ((row & 7) << 4)));
            }
#pragma unroll
            for (int fm = 0; fm < 4; ++fm)
#pragma unroll
                for (int fn = 0; fn < 4; ++fn)
                    s[fm][fn] = __builtin_amdgcn_mfma_f32_16x16x32_bf16(
                        qf[fm][kk], kf[fn], s[fm][fn], 0, 0, 0);
        }
        const bool diag = (kt == w);
#pragma unroll
        for (int fm = 0; fm < 4; ++fm) {
#pragma unroll
            for (int r = 0; r < 4; ++r) {
                int rowg = r0 + fm*16 + g*4 + r;
                float mx = -1e30f;
#pragma unroll
                for (int fn = 0; fn < 4; ++fn) {
                    float val = s[fm][fn][r] * 0.125f;
                    if (diag) {
                        int colg = kt*64 + fn*16 + l15;
                        if (colg > rowg) val = -1e30f;
                    }
                    s[fm][fn][r] = val;
                    mx = fmaxf(mx, val);
                }
                mx = fmaxf(mx, __shfl_xor(mx, 1));
                mx = fmaxf(mx, __shfl_xor(mx, 2));
                mx = fmaxf(mx, __shfl_xor(mx, 4));
                mx = fmaxf(mx, __shfl_xor(mx, 8));
                float mnew = fmaxf(mst[fm][r], mx);
                float sf   = __expf(mst[fm][r] - mnew);
                mst[fm][r] = mnew;
                float rowsum = 0.f;
#pragma unroll
                for (int fn = 0; fn < 4; ++fn) {
                    float pe = __expf(s[fm][fn][r] - mnew);
                    s[fm][fn][r] = pe;
                    rowsum += pe;
                }
                rowsum += __shfl_xor(rowsum, 1);
                rowsum += __shfl_xor(rowsum, 2);
                rowsum += __shfl_xor(rowsum, 4);
                rowsum += __shfl_xor(rowsum, 8);
                lst[fm][r] = lst[fm][r] * sf + rowsum;
#pragma unroll
                for (int fd = 0; fd < 4; ++fd) oacc[fm][fd][r] *= sf;
                int prow = fm*16 + g*4 + r;
#pragma unroll
                for (int fn = 0; fn < 4; ++fn) {
                    int pcol = fn*16 + l15;
                    *(u16*)((char*)Ps[w] + prow*128 +
                            ((pcol*2) ^ ((prow & 7) << 4))) = f2bf(s[fm][fn][r]);
                }
            }
        }
        asm volatile("s_waitcnt lgkmcnt(0)" ::: "memory");  // P writes visible
#pragma unroll
        for (int kk2 = 0; kk2 < 2; ++kk2) {
            bf16x8 pa[4], vb[4];
#pragma unroll
            for (int fm = 0; fm < 4; ++fm) {
                int prow = fm*16 + l15;
                pa[fm] = *(const bf16x8*)((char*)Ps[w] + prow*128 +
                          ((kk2*64 + g*16) ^ ((prow & 7) << 4)));
            }
#pragma unroll
            for (int fd = 0; fd < 4; ++fd) {
                int vrow = fd*16 + l15;
                vb[fd] = *(const bf16x8*)((char*)Vt + vrow*512 +
                          ((kt*128 + kk2*64 + g*16) ^ ((vrow & 7) << 4)));
            }
#pragma unroll
            for (int fm = 0; fm < 4; ++fm)
#pragma unroll
                for (int fd = 0; fd < 4; ++fd)
                    oacc[fm][fd] = __builtin_amdgcn_mfma_f32_16x16x32_bf16(
                        pa[fm], vb[fd], oacc[fm][fd], 0, 0, 0);
        }
    }
    // write O (bf16), normalized by row sums
#pragma unroll
    for (int fm = 0; fm < 4; ++fm)
#pragma unroll
        for (int r = 0; r < 4; ++r) {
            int rowg = r0 + fm*16 + g*4 + r;
            float inv = 1.f / lst[fm][r];
#pragma unroll
            for (int fd = 0; fd < 4; ++fd)
                op[((size_t)b * 256 + rowg) * 384 + hh*64 + fd*16 + l15] =
                    f2bf(oacc[fm][fd][r] * inv);
        }
}

// ---------------------------------------------------------------------------
// Head GEMM (N=65) + log-softmax loss. One wave per row; whT [65][384] bf16.
// grid = 65536/4
// ---------------------------------------------------------------------------
__global__ __launch_bounds__(256)
void head_loss_k(const u16* __restrict__ h, const u16* __restrict__ whT,
                 const float* __restrict__ bhp, const int* __restrict__ tgt,
                 float* __restrict__ logits, float* __restrict__ lossbuf)
{
    __shared__ u16 rows[4][384];
    __shared__ float wloss[4];
    const int lane = threadIdx.x & 63;
    const int w    = threadIdx.x >> 6;
    const size_t row = (size_t)blockIdx.x * 4 + w;

    const u32* hr = (const u32*)(h + row * 384);
    u32* lr = (u32*)rows[w];
    lr[lane]       = hr[lane];
    lr[64 + lane]  = hr[64 + lane];
    lr[128 + lane] = hr[128 + lane];
    asm volatile("s_waitcnt lgkmcnt(0)" ::: "memory");

    const uint4* xr = (const uint4*)rows[w];
    const uint4* wr = (const uint4*)(whT + (size_t)lane * 384);
    float acc = bhp[lane];
#pragma unroll 4
    for (int i = 0; i < 48; ++i) acc += dot8(wr[i], xr[i]);

    // 65th column (n=64), distributed across lanes
    const uint4* wr2 = (const uint4*)(whT + (size_t)64 * 384);
    float p64 = (lane < 48) ? dot8(wr2[lane], xr[lane]) : 0.f;
#pragma unroll
    for (int m = 1; m < 64; m <<= 1) p64 += __shfl_xor(p64, m);
    float l64 = p64 + bhp[64];

    logits[row * 65 + lane] = acc;
    if (lane == 0) logits[row * 65 + 64] = l64;

    float mx = acc;
#pragma unroll
    for (int m = 1; m < 64; m <<= 1) mx = fmaxf(mx, __shfl_xor(mx, m));
    mx = fmaxf(mx, l64);
    float e = __expf(acc - mx);
#pragma unroll
    for (int m = 1; m < 64; m <<= 1) e += __shfl_xor(e, m);
    e += __expf(l64 - mx);
    float lse = mx + logf(e);
    int t = tgt[row];
    float lt0 = __shfl(acc, t < 64 ? t : 0);
    float lt  = (t < 64) ? lt0 : l64;
    if (lane == 0) wloss[w] = lse - lt;
    __syncthreads();
    if (threadIdx.x == 0) {
        float bsum = wloss[0] + wloss[1] + wloss[2] + wloss[3];
        atomicAdd(&lossbuf[blockIdx.x & 31], bsum * (1.f / 65536.f));
    }
}

__global__ void loss_finish_k(const float* __restrict__ part, float* __restrict__ outp)
{
    int lane = threadIdx.x;
    float v = (lane < 32) ? part[lane] : 0.f;
#pragma unroll
    for (int m = 1; m < 64; m <<= 1) v += __shfl_xor(v, m);
    if (lane == 0) outp[0] = v;
}

// ---------------------------------------------------------------------------
extern "C" void kernel_launch(void* const* d_in, const int* in_sizes, int n_in,
                              void* d_out, int out_size, void* d_ws, size_t ws_size,
                              hipStream_t stream)
{
    (void)in_sizes; (void)n_in; (void)out_size; (void)ws_size;
    const int*   idx  = (const int*)d_in[0];
    const int*   tgt  = (const int*)d_in[1];
    const float* tok  = (const float*)d_in[2];
    const float* pos  = (const float*)d_in[3];
    const float* Wq   = (const float*)d_in[4];
    const float* Wk   = (const float*)d_in[5];
    const float* Wv   = (const float*)d_in[6];
    const float* Wo   = (const float*)d_in[7];
    const float* bo   = (const float*)d_in[8];
    const float* ln1g = (const float*)d_in[9];
    const float* ln1b = (const float*)d_in[10];
    const float* ln2g = (const float*)d_in[11];
    const float* ln2b = (const float*)d_in[12];
    const float* W1   = (const float*)d_in[13];
    const float* b1   = (const float*)d_in[14];
    const float* W2   = (const float*)d_in[15];
    const float* b2   = (const float*)d_in[16];
    const float* lnfg = (const float*)d_in[17];
    const float* lnfb = (const float*)d_in[18];
    const float* Wh   = (const float*)d_in[19];
    const float* bh   = (const float*)d_in[20];

    // ---- workspace layout (~172.3 MB) ----
    char* p = (char*)d_ws;
    u16* x    = (u16*)p;  p += (size_t)65536*384*2;      // residual, bf16 (50.3M)
    u16* hbuf = (u16*)p;  p += (size_t)65536*384*2;      // LN out / attn O (50.3M)
    u16* r1   = (u16*)p;  p += (size_t)16384*1536*2;     // qkv chunk / ff chunk (50.3M)
    u16* wqkv = (u16*)p;  p += (size_t)6*1152*384*2;     // [L][1152][384]
    u16* wto  = (u16*)p;  p += (size_t)6*384*384*2;      // [L][384][384]
    u16* wt1  = (u16*)p;  p += (size_t)6*1536*384*2;     // [L][1536][384]
    u16* wt2  = (u16*)p;  p += (size_t)6*384*1536*2;     // [L][384][1536]
    u16* wth  = (u16*)p;  p += (size_t)65*384*2 + 64;    // [65][384]
    float* lossbuf = (float*)p;                          // 32 f32 partials

    float* out   = (float*)d_out;
    float* lossp = out + (size_t)65536 * 65;

    // ---- weight prep (bf16, transposed to [N][K]) ----
    convT_k<<<1024, 256, 0, stream>>>(Wq, wqkv, 6, 384, 384, 442368, 0);
    convT_k<<<1024, 256, 0, stream>>>(Wk, wqkv, 6, 384, 384, 442368, 384);
    convT_k<<<1024, 256, 0, stream>>>(Wv, wqkv, 6, 384, 384, 442368, 768);
    convT_k<<<1024, 256, 0, stream>>>(Wo, wto, 6, 384, 384, 147456, 0);
    convT_k<<<2048, 256, 0, stream>>>(W1, wt1, 6, 384, 1536, 589824, 0);
    convT_k<<<2048, 256, 0, stream>>>(W2, wt2, 6, 1536, 384, 589824, 0);
    convT_k<<<64,   256, 0, stream>>>(Wh, wth, 1, 384, 65, 24960, 0);

    embed_k<<<12288, 256, 0, stream>>>(idx, tok, pos, x, lossbuf);

    for (int l = 0; l < 6; ++l) {
        ln_k<<<16384, 256, 0, stream>>>(x, ln1g + l*384, ln1b + l*384, hbuf);
        for (int ac = 0; ac < 4; ++ac) {                 // 64 batches per chunk
            const size_t ro = (size_t)ac * 16384;
            gemm_bt<0><<<dim3(128, 9), 256, 0, stream>>>(
                hbuf + ro*384, wqkv + (size_t)l*442368, r1, nullptr, 384, 1152);
            attn_k<<<384, 256, 0, stream>>>(r1, hbuf + ro*384);
        }
        gemm_bt<2><<<dim3(512, 3), 256, 0, stream>>>(
            hbuf, wto + (size_t)l*147456, x, bo + l*384, 384, 384);
        ln_k<<<16384, 256, 0, stream>>>(x, ln2g + l*384, ln2b + l*384, hbuf);
        for (int mc = 0; mc < 4; ++mc) {                 // 16384 rows per chunk
            const size_t ro = (size_t)mc * 16384;
            gemm_bt<1><<<dim3(128, 12), 256, 0, stream>>>(
                hbuf + ro*384, wt1 + (size_t)l*589824, r1, b1 + l*1536, 384, 1536);
            gemm_bt<2><<<dim3(128, 3), 256, 0, stream>>>(
                r1, wt2 + (size_t)l*589824, x + ro*384, b2 + l*384, 1536, 384);
        }
    }
    ln_k<<<16384, 256, 0, stream>>>(x, lnfg, lnfb, hbuf);
    head_loss_k<<<16384, 256, 0, stream>>>(hbuf, wth, bh, tgt, out, lossbuf);
    loss_finish_k<<<1, 64, 0, stream>>>(lossbuf, lossp);
}

// Round 6
// 3960.080 us; speedup vs baseline: 1.2623x; 1.2623x over previous
//
#include <hip/hip_runtime.h>
#include <stdint.h>

// ---------------------------------------------------------------------------
// NanoGPT forward (L=6,H=6,C=384,T=256,V=65,B=256) on gfx950.
// Residual x in bf16; GEMMs bf16 MFMA (f32 accum); flash attention per (b,h).
// Workspace adaptive: NC=1 (324MB) / NC=2 (223MB) / NC=4 (172MB) chunking.
// ---------------------------------------------------------------------------

typedef unsigned short u16;
typedef unsigned int   u32;
typedef __attribute__((ext_vector_type(8))) short bf16x8;   // 8 bf16 (4 VGPR)
typedef __attribute__((ext_vector_type(4))) float f32x4;    // MFMA accumulator

typedef const __attribute__((address_space(1))) void* gas_ptr;
typedef __attribute__((address_space(3))) void* lds_ptr;

__device__ __forceinline__ void gld_lds16(const void* g, void* l) {
    __builtin_amdgcn_global_load_lds((gas_ptr)g, (lds_ptr)l, 16, 0, 0);
}

__device__ __forceinline__ u16 f2bf(float f) {          // RNE f32->bf16
    u32 u = __builtin_bit_cast(u32, f);
    u = u + 0x7fffu + ((u >> 16) & 1u);
    return (u16)(u >> 16);
}
__device__ __forceinline__ float bf2f(u16 h) { return __builtin_bit_cast(float, (u32)h << 16); }
__device__ __forceinline__ float bflo(u32 u) { return __builtin_bit_cast(float, u << 16); }
__device__ __forceinline__ float bfhi(u32 u) { return __builtin_bit_cast(float, u & 0xffff0000u); }

// ---------------------------------------------------------------------------
// Convert+transpose: src f32 [L][R][C] -> dst bf16, dst[l*dls + (dco+c)*R + r]
// ---------------------------------------------------------------------------
__global__ __launch_bounds__(256)
void convT_k(const float* __restrict__ src, u16* __restrict__ dst,
             int L, int R, int C, int dls, int dco)
{
    size_t total  = (size_t)L * R * C;
    size_t stride = (size_t)gridDim.x * 256;
    for (size_t i = (size_t)blockIdx.x * 256 + threadIdx.x; i < total; i += stride) {
        size_t rc  = (size_t)R * C;
        size_t l   = i / rc;
        size_t rem = i - l * rc;
        int r = (int)(rem / C);
        int c = (int)(rem - (size_t)r * C);
        dst[l * (size_t)dls + (size_t)(dco + c) * R + r] = f2bf(src[i]);
    }
}

// ---------------------------------------------------------------------------
// Embedding: x[row][c] = bf16(tok_emb[idx[row]][c] + pos_emb[row%256][c])
// grid*256 = 65536*48 (8-elem groups). Also zeroes the 32-entry loss buffer.
// ---------------------------------------------------------------------------
__global__ __launch_bounds__(256)
void embed_k(const int* __restrict__ idx, const float* __restrict__ tok,
             const float* __restrict__ pos, u16* __restrict__ x,
             float* __restrict__ lossbuf)
{
    if (blockIdx.x == 0 && threadIdx.x < 32) lossbuf[threadIdx.x] = 0.f;
    int gi  = blockIdx.x * 256 + threadIdx.x;
    int row = gi / 48;
    int cg  = gi - row * 48;
    int t   = row & 255;
    const float4* ta = (const float4*)(tok + (size_t)idx[row] * 384 + cg * 8);
    const float4* pa = (const float4*)(pos + (size_t)t * 384 + cg * 8);
    float4 a0 = ta[0], a1 = ta[1], p0 = pa[0], p1 = pa[1];
    u16 o[8] = { f2bf(a0.x+p0.x), f2bf(a0.y+p0.y), f2bf(a0.z+p0.z), f2bf(a0.w+p0.w),
                 f2bf(a1.x+p1.x), f2bf(a1.y+p1.y), f2bf(a1.z+p1.z), f2bf(a1.w+p1.w) };
    *(uint4*)(x + (size_t)row * 384 + cg * 8) = *(uint4*)o;
}

// ---------------------------------------------------------------------------
// LayerNorm over C=384 (bf16 in, bf16 out): one wave per row. grid = 65536/4
// ---------------------------------------------------------------------------
__global__ __launch_bounds__(256)
void ln_k(const u16* __restrict__ x, const float* __restrict__ gg,
          const float* __restrict__ bb, u16* __restrict__ out)
{
    const int lane = threadIdx.x & 63;
    const int w    = threadIdx.x >> 6;
    const size_t row = (size_t)blockIdx.x * 4 + w;
    const u32* xr = (const u32*)(x + row * 384);
    u32 d[3] = { xr[lane], xr[64 + lane], xr[128 + lane] };
    float v[6];
#pragma unroll
    for (int k = 0; k < 3; ++k) { v[2*k] = bflo(d[k]); v[2*k+1] = bfhi(d[k]); }
    float s = 0.f, sq = 0.f;
#pragma unroll
    for (int j = 0; j < 6; ++j) { s += v[j]; sq += v[j]*v[j]; }
#pragma unroll
    for (int m = 1; m < 64; m <<= 1) { s += __shfl_xor(s, m); sq += __shfl_xor(sq, m); }
    float mean = s * (1.f / 384.f);
    float var  = sq * (1.f / 384.f) - mean * mean;
    float rs   = rsqrtf(var + 1e-5f);
    u32* orow = (u32*)(out + row * 384);
#pragma unroll
    for (int k = 0; k < 3; ++k) {
        int c = k * 128 + 2 * lane;
        float o0 = (v[2*k]   - mean) * rs * gg[c]   + bb[c];
        float o1 = (v[2*k+1] - mean) * rs * gg[c+1] + bb[c+1];
        orow[k*64 + lane] = (u32)f2bf(o0) | ((u32)f2bf(o1) << 16);
    }
}

// ---------------------------------------------------------------------------
// GEMM: A[M,K] bf16 row-major x Bt[N,K] bf16 (pre-transposed) -> C [M,N]
// 128x128 tile, BK=32, 4 waves (2x2 of 64x64), mfma 16x16x32 bf16.
// global_load_lds(16B) staging, double-buffered, XOR-swizzle via pre-swizzled
// global source (T21).
// EPI: 0 = bf16 store, 1 = bias+relu bf16, 2 = bf16 residual rmw (+bias),
//      3 = f32 store (+bias), cols guarded to N (head logits)
// ---------------------------------------------------------------------------
template<int EPI>
__global__ __launch_bounds__(256)
void gemm_bt(const u16* __restrict__ A, const u16* __restrict__ Bt,
             u16* __restrict__ C, float* __restrict__ Cf,
             const float* __restrict__ bias, int K, int N)
{
    __shared__ u16 As[2][128*32];
    __shared__ u16 Bs[2][128*32];
    const int tid = threadIdx.x;
    const int lane = tid & 63;
    const int w  = tid >> 6;
    const int wm = w >> 1, wn = w & 1;
    const int m0 = blockIdx.x * 128;
    const int n0 = blockIdx.y * 128;
    const int g   = lane >> 4;
    const int l15 = lane & 15;

    f32x4 acc[4][4] = {};
    const int nk = K >> 5;

    auto stage = [&](int buf, int t) {
        const int k0 = t << 5;
#pragma unroll
        for (int c = 0; c < 2; ++c) {
            int i   = c * 256 + tid;
            int row = i >> 2;                       // 0..127
            int seg = (i & 3) ^ (row & 3);          // pre-swizzled source
            gld_lds16(A  + (size_t)(m0 + row) * K + k0 + seg * 8,
                      (char*)(&As[buf][0]) + (c * 256 + w * 64) * 16);
            gld_lds16(Bt + (size_t)(n0 + row) * K + k0 + seg * 8,
                      (char*)(&Bs[buf][0]) + (c * 256 + w * 64) * 16);
        }
    };

    stage(0, 0);
    __syncthreads();
    int cur = 0;
    for (int t = 0; t < nk; ++t) {
        if (t + 1 < nk) stage(cur ^ 1, t + 1);
        const char* Ab = (const char*)&As[cur][0];
        const char* Bb = (const char*)&Bs[cur][0];
        bf16x8 af[4], bfv[4];
#pragma unroll
        for (int fm = 0; fm < 4; ++fm) {
            int row = wm*64 + fm*16 + l15;
            af[fm] = *(const bf16x8*)(Ab + row*64 + ((g ^ (row & 3)) * 16));
        }
#pragma unroll
        for (int fn = 0; fn < 4; ++fn) {
            int row = wn*64 + fn*16 + l15;
            bfv[fn] = *(const bf16x8*)(Bb + row*64 + ((g ^ (row & 3)) * 16));
        }
#pragma unroll
        for (int fm = 0; fm < 4; ++fm)
#pragma unroll
            for (int fn = 0; fn < 4; ++fn)
                acc[fm][fn] = __builtin_amdgcn_mfma_f32_16x16x32_bf16(
                    af[fm], bfv[fn], acc[fm][fn], 0, 0, 0);
        __syncthreads();
        cur ^= 1;
    }

    // epilogue: D row = base + (lane>>4)*4 + r, col = base + (lane&15)
#pragma unroll
    for (int fm = 0; fm < 4; ++fm) {
        int rowb = m0 + wm*64 + fm*16 + g*4;
#pragma unroll
        for (int fn = 0; fn < 4; ++fn) {
            int col = n0 + wn*64 + fn*16 + l15;
            float bv = (EPI == 0) ? 0.f
                     : ((EPI == 3 && col >= N) ? 0.f : bias[col]);
#pragma unroll
            for (int r = 0; r < 4; ++r) {
                size_t off = (size_t)(rowb + r) * N + col;
                float vv = acc[fm][fn][r];
                if (EPI == 0) {
                    C[off] = f2bf(vv);
                } else if (EPI == 1) {
                    vv += bv; vv = vv > 0.f ? vv : 0.f;
                    C[off] = f2bf(vv);
                } else if (EPI == 2) {
                    C[off] = f2bf(bf2f(C[off]) + vv + bv);
                } else {
                    if (col < N) Cf[off] = vv + bv;
                }
            }
        }
    }
}

// ---------------------------------------------------------------------------
// Flash attention, one block per (b_local, h). qkv interleaved [row][1152].
// K [256][64], Vt [64][256], per-wave P [64][64] in LDS, XOR-swizzled.
// Online softmax, causal. O -> op rows [b*256+t][384].
// ---------------------------------------------------------------------------
__global__ __launch_bounds__(256)
void attn_k(const u16* __restrict__ qkv, u16* __restrict__ op)
{
    __shared__ u16 Ks[256*64];        // 32 KiB
    __shared__ u16 Vt[64*256];        // 32 KiB (transposed)
    __shared__ u16 Ps[4][64*64];      // 32 KiB (per-wave)
    const int tid  = threadIdx.x;
    const int lane = tid & 63;
    const int w    = tid >> 6;
    const int g    = lane >> 4;
    const int l15  = lane & 15;
    const int bh = blockIdx.x;
    const int b  = bh / 6, hh = bh - b * 6;
    const size_t baseQ = (size_t)b * 256 * 1152 + hh * 64;
    const size_t baseK = baseQ + 384;
    const size_t baseV = baseQ + 768;

#pragma unroll
    for (int cc = 0; cc < 8; ++cc) {
        int i    = cc * 256 + tid;
        int row  = i >> 3;
        int slot = (i & 7) ^ (row & 7);
        gld_lds16(qkv + baseK + (size_t)row * 1152 + slot * 8,
                  (char*)Ks + (cc * 256 + w * 64) * 16);
    }
#pragma unroll
    for (int it = 0; it < 16; ++it) {
        int j    = it * 256 + tid;
        int trow = j >> 4;
        int d0   = (j & 15) * 4;
        uint2 val = *(const uint2*)(qkv + baseV + (size_t)trow * 1152 + d0);
        u16 e0 = (u16)(val.x & 0xffff), e1 = (u16)(val.x >> 16);
        u16 e2 = (u16)(val.y & 0xffff), e3 = (u16)(val.y >> 16);
        *(u16*)((char*)Vt + (d0+0)*512 + ((trow*2) ^ (((d0+0)&7) << 4))) = e0;
        *(u16*)((char*)Vt + (d0+1)*512 + ((trow*2) ^ (((d0+1)&7) << 4))) = e1;
        *(u16*)((char*)Vt + (d0+2)*512 + ((trow*2) ^ (((d0+2)&7) << 4))) = e2;
        *(u16*)((char*)Vt + (d0+3)*512 + ((trow*2) ^ (((d0+3)&7) << 4))) = e3;
    }
    __syncthreads();

    const int r0 = w * 64;
    bf16x8 qf[4][2];
#pragma unroll
    for (int fm = 0; fm < 4; ++fm)
#pragma unroll
        for (int kk = 0; kk < 2; ++kk)
            qf[fm][kk] = *(const bf16x8*)(qkv + baseQ +
                (size_t)(r0 + fm*16 + l15) * 1152 + kk*32 + g*8);

    f32x4 oacc[4][4] = {};
    float mst[4][4], lst[4][4];
#pragma unroll
    for (int i = 0; i < 4; ++i)
#pragma unroll
        for (int r = 0; r < 4; ++r) { mst[i][r] = -1e30f; lst[i][r] = 0.f; }

    for (int kt = 0; kt <= w; ++kt) {
        f32x4 s[4][4] = {};
#pragma unroll
        for (int kk = 0; kk < 2; ++kk) {
            bf16x8 kf[4];
#pragma unroll
            for (int fn = 0; fn < 4; ++fn) {
                int row = kt*64 + fn*16 + l15;
                kf[fn] = *(const bf16x8*)((char*)Ks + row*128 +
                          ((kk*64 + g*16) ^ ((row & 7) << 4)));
            }
#pragma unroll
            for (int fm = 0; fm < 4; ++fm)
#pragma unroll
                for (int fn = 0; fn < 4; ++fn)
                    s[fm][fn] = __builtin_amdgcn_mfma_f32_16x16x32_bf16(
                        qf[fm][kk], kf[fn], s[fm][fn], 0, 0, 0);
        }
        const bool diag = (kt == w);
#pragma unroll
        for (int fm = 0; fm < 4; ++fm) {
#pragma unroll
            for (int r = 0; r < 4; ++r) {
                int rowg = r0 + fm*16 + g*4 + r;
                float mx = -1e30f;
#pragma unroll
                for (int fn = 0; fn < 4; ++fn) {
                    float val = s[fm][fn][r] * 0.125f;
                    if (diag) {
                        int colg = kt*64 + fn*16 + l15;
                        if (colg > rowg) val = -1e30f;
                    }
                    s[fm][fn][r] = val;
                    mx = fmaxf(mx, val);
                }
                mx = fmaxf(mx, __shfl_xor(mx, 1));
                mx = fmaxf(mx, __shfl_xor(mx, 2));
                mx = fmaxf(mx, __shfl_xor(mx, 4));
                mx = fmaxf(mx, __shfl_xor(mx, 8));
                float mnew = fmaxf(mst[fm][r], mx);
                float sf   = __expf(mst[fm][r] - mnew);
                mst[fm][r] = mnew;
                float rowsum = 0.f;
#pragma unroll
                for (int fn = 0; fn < 4; ++fn) {
                    float pe = __expf(s[fm][fn][r] - mnew);
                    s[fm][fn][r] = pe;
                    rowsum += pe;
                }
                rowsum += __shfl_xor(rowsum, 1);
                rowsum += __shfl_xor(rowsum, 2);
                rowsum += __shfl_xor(rowsum, 4);
                rowsum += __shfl_xor(rowsum, 8);
                lst[fm][r] = lst[fm][r] * sf + rowsum;
#pragma unroll
                for (int fd = 0; fd < 4; ++fd) oacc[fm][fd][r] *= sf;
                int prow = fm*16 + g*4 + r;
#pragma unroll
                for (int fn = 0; fn < 4; ++fn) {
                    int pcol = fn*16 + l15;
                    *(u16*)((char*)Ps[w] + prow*128 +
                            ((pcol*2) ^ ((prow & 7) << 4))) = f2bf(s[fm][fn][r]);
                }
            }
        }
        asm volatile("s_waitcnt lgkmcnt(0)" ::: "memory");
#pragma unroll
        for (int kk2 = 0; kk2 < 2; ++kk2) {
            bf16x8 pa[4], vb[4];
#pragma unroll
            for (int fm = 0; fm < 4; ++fm) {
                int prow = fm*16 + l15;
                pa[fm] = *(const bf16x8*)((char*)Ps[w] + prow*128 +
                          ((kk2*64 + g*16) ^ ((prow & 7) << 4)));
            }
#pragma unroll
            for (int fd = 0; fd < 4; ++fd) {
                int vrow = fd*16 + l15;
                vb[fd] = *(const bf16x8*)((char*)Vt + vrow*512 +
                          ((kt*128 + kk2*64 + g*16) ^ ((vrow & 7) << 4)));
            }
#pragma unroll
            for (int fm = 0; fm < 4; ++fm)
#pragma unroll
                for (int fd = 0; fd < 4; ++fd)
                    oacc[fm][fd] = __builtin_amdgcn_mfma_f32_16x16x32_bf16(
                        pa[fm], vb[fd], oacc[fm][fd], 0, 0, 0);
        }
    }
#pragma unroll
    for (int fm = 0; fm < 4; ++fm)
#pragma unroll
        for (int r = 0; r < 4; ++r) {
            int rowg = r0 + fm*16 + g*4 + r;
            float inv = 1.f / lst[fm][r];
#pragma unroll
            for (int fd = 0; fd < 4; ++fd)
                op[((size_t)b * 256 + rowg) * 384 + hh*64 + fd*16 + l15] =
                    f2bf(oacc[fm][fd][r] * inv);
        }
}

// ---------------------------------------------------------------------------
// Loss from f32 logits [65536][65]: one wave per row, grid = 65536/4.
// ---------------------------------------------------------------------------
__global__ __launch_bounds__(256)
void loss_k(const float* __restrict__ logits, const int* __restrict__ tgt,
            float* __restrict__ lossbuf)
{
    __shared__ float wloss[4];
    const int lane = threadIdx.x & 63;
    const int w    = threadIdx.x >> 6;
    const size_t row = (size_t)blockIdx.x * 4 + w;
    const float* lr = logits + row * 65;
    float v   = lr[lane];
    float l64 = lr[64];
    float mx = v;
#pragma unroll
    for (int m = 1; m < 64; m <<= 1) mx = fmaxf(mx, __shfl_xor(mx, m));
    mx = fmaxf(mx, l64);
    float e = __expf(v - mx);
#pragma unroll
    for (int m = 1; m < 64; m <<= 1) e += __shfl_xor(e, m);
    e += __expf(l64 - mx);
    float lse = mx + logf(e);
    int t = tgt[row];
    float lt0 = __shfl(v, t < 64 ? t : 0);
    float lt  = (t < 64) ? lt0 : l64;
    if (lane == 0) wloss[w] = lse - lt;
    __syncthreads();
    if (threadIdx.x == 0) {
        float bsum = wloss[0] + wloss[1] + wloss[2] + wloss[3];
        atomicAdd(&lossbuf[blockIdx.x & 31], bsum * (1.f / 65536.f));
    }
}

__global__ void loss_finish_k(const float* __restrict__ part, float* __restrict__ outp)
{
    int lane = threadIdx.x;
    float v = (lane < 32) ? part[lane] : 0.f;
#pragma unroll
    for (int m = 1; m < 64; m <<= 1) v += __shfl_xor(v, m);
    if (lane == 0) outp[0] = v;
}

// ---------------------------------------------------------------------------
extern "C" void kernel_launch(void* const* d_in, const int* in_sizes, int n_in,
                              void* d_out, int out_size, void* d_ws, size_t ws_size,
                              hipStream_t stream)
{
    (void)in_sizes; (void)n_in; (void)out_size;
    const int*   idx  = (const int*)d_in[0];
    const int*   tgt  = (const int*)d_in[1];
    const float* tok  = (const float*)d_in[2];
    const float* pos  = (const float*)d_in[3];
    const float* Wq   = (const float*)d_in[4];
    const float* Wk   = (const float*)d_in[5];
    const float* Wv   = (const float*)d_in[6];
    const float* Wo   = (const float*)d_in[7];
    const float* bo   = (const float*)d_in[8];
    const float* ln1g = (const float*)d_in[9];
    const float* ln1b = (const float*)d_in[10];
    const float* ln2g = (const float*)d_in[11];
    const float* ln2b = (const float*)d_in[12];
    const float* W1   = (const float*)d_in[13];
    const float* b1   = (const float*)d_in[14];
    const float* W2   = (const float*)d_in[15];
    const float* b2   = (const float*)d_in[16];
    const float* lnfg = (const float*)d_in[17];
    const float* lnfb = (const float*)d_in[18];
    const float* Wh   = (const float*)d_in[19];
    const float* bh   = (const float*)d_in[20];

    // ---- adaptive chunk count based on ws_size ----
    const size_t fixed = (size_t)65536*384*2 * 2        // x + hbuf
                       + (size_t)6*1152*384*2           // wqkv
                       + (size_t)6*384*384*2            // wto
                       + (size_t)6*1536*384*2 * 2       // wt1 + wt2
                       + (size_t)128*384*2 + 4096;      // wth (padded) + loss/slack
    int NC = 4;
    if      (ws_size >= fixed + (size_t)65536*1536*2)      NC = 1;
    else if (ws_size >= fixed + (size_t)32768*1536*2)      NC = 2;
    const int CR = 65536 / NC;                           // rows per chunk

    // ---- workspace layout ----
    char* p = (char*)d_ws;
    u16* x    = (u16*)p;  p += (size_t)65536*384*2;      // residual bf16
    u16* hbuf = (u16*)p;  p += (size_t)65536*384*2;      // LN out / attn O
    u16* r1   = (u16*)p;  p += (size_t)CR*1536*2;        // qkv / ff chunk
    u16* wqkv = (u16*)p;  p += (size_t)6*1152*384*2;     // [L][1152][384]
    u16* wto  = (u16*)p;  p += (size_t)6*384*384*2;      // [L][384][384]
    u16* wt1  = (u16*)p;  p += (size_t)6*1536*384*2;     // [L][1536][384]
    u16* wt2  = (u16*)p;  p += (size_t)6*384*1536*2;     // [L][384][1536]
    u16* wth  = (u16*)p;  p += (size_t)128*384*2;        // [65->128 pad][384]
    float* lossbuf = (float*)p;                          // 32 f32 partials

    float* out   = (float*)d_out;
    float* lossp = out + (size_t)65536 * 65;

    // ---- weight prep (bf16, transposed to [N][K]) ----
    convT_k<<<1024, 256, 0, stream>>>(Wq, wqkv, 6, 384, 384, 442368, 0);
    convT_k<<<1024, 256, 0, stream>>>(Wk, wqkv, 6, 384, 384, 442368, 384);
    convT_k<<<1024, 256, 0, stream>>>(Wv, wqkv, 6, 384, 384, 442368, 768);
    convT_k<<<1024, 256, 0, stream>>>(Wo, wto, 6, 384, 384, 147456, 0);
    convT_k<<<2048, 256, 0, stream>>>(W1, wt1, 6, 384, 1536, 589824, 0);
    convT_k<<<2048, 256, 0, stream>>>(W2, wt2, 6, 1536, 384, 589824, 0);
    convT_k<<<64,   256, 0, stream>>>(Wh, wth, 1, 384, 65, 24960, 0);

    embed_k<<<12288, 256, 0, stream>>>(idx, tok, pos, x, lossbuf);

    for (int l = 0; l < 6; ++l) {
        ln_k<<<16384, 256, 0, stream>>>(x, ln1g + l*384, ln1b + l*384, hbuf);
        for (int ac = 0; ac < NC; ++ac) {
            const size_t ro = (size_t)ac * CR;
            gemm_bt<0><<<dim3(CR/128, 9), 256, 0, stream>>>(
                hbuf + ro*384, wqkv + (size_t)l*442368, r1, nullptr, nullptr, 384, 1152);
            attn_k<<<(CR/256)*6, 256, 0, stream>>>(r1, hbuf + ro*384);
        }
        gemm_bt<2><<<dim3(512, 3), 256, 0, stream>>>(
            hbuf, wto + (size_t)l*147456, x, nullptr, bo + l*384, 384, 384);
        ln_k<<<16384, 256, 0, stream>>>(x, ln2g + l*384, ln2b + l*384, hbuf);
        for (int mc = 0; mc < NC; ++mc) {
            const size_t ro = (size_t)mc * CR;
            gemm_bt<1><<<dim3(CR/128, 12), 256, 0, stream>>>(
                hbuf + ro*384, wt1 + (size_t)l*589824, r1, nullptr, b1 + l*1536, 384, 1536);
            gemm_bt<2><<<dim3(CR/128, 3), 256, 0, stream>>>(
                r1, wt2 + (size_t)l*589824, x + ro*384, nullptr, b2 + l*384, 1536, 384);
        }
    }
    ln_k<<<16384, 256, 0, stream>>>(x, lnfg, lnfb, hbuf);
    // head: logits (f32, +bias) straight to d_out via MFMA GEMM, cols<65
    gemm_bt<3><<<dim3(512, 1), 256, 0, stream>>>(
        hbuf, wth, nullptr, out, bh, 384, 65);
    loss_k<<<16384, 256, 0, stream>>>(out, tgt, lossbuf);
    loss_finish_k<<<1, 64, 0, stream>>>(lossbuf, lossp);
}

// Round 10
// 3838.711 us; speedup vs baseline: 1.3022x; 1.0316x over previous
//
#include <hip/hip_runtime.h>
#include <stdint.h>

// ---------------------------------------------------------------------------
// NanoGPT forward (L=6,H=6,C=384,T=256,V=65,B=256) on gfx950.
// Residual x in bf16; GEMMs bf16 MFMA (f32 accum); flash attention per (b,h).
// GEMM grid: A-panel-major + XCD-chunk swizzle (weights are L2-resident).
// ---------------------------------------------------------------------------

typedef unsigned short u16;
typedef unsigned int   u32;
typedef __attribute__((ext_vector_type(8))) short bf16x8;   // 8 bf16 (4 VGPR)
typedef __attribute__((ext_vector_type(4))) float f32x4;    // MFMA accumulator

typedef const __attribute__((address_space(1))) void* gas_ptr;
typedef __attribute__((address_space(3))) void* lds_ptr;

__device__ __forceinline__ void gld_lds16(const void* g, void* l) {
    __builtin_amdgcn_global_load_lds((gas_ptr)g, (lds_ptr)l, 16, 0, 0);
}

__device__ __forceinline__ u16 f2bf(float f) {          // RNE f32->bf16
    u32 u = __builtin_bit_cast(u32, f);
    u = u + 0x7fffu + ((u >> 16) & 1u);
    return (u16)(u >> 16);
}
__device__ __forceinline__ float bf2f(u16 h) { return __builtin_bit_cast(float, (u32)h << 16); }
__device__ __forceinline__ float bflo(u32 u) { return __builtin_bit_cast(float, u << 16); }
__device__ __forceinline__ float bfhi(u32 u) { return __builtin_bit_cast(float, u & 0xffff0000u); }

// ---------------------------------------------------------------------------
// Convert+transpose: src f32 [L][R][C] -> dst bf16, dst[l*dls + (dco+c)*R + r]
// ---------------------------------------------------------------------------
__global__ __launch_bounds__(256)
void convT_k(const float* __restrict__ src, u16* __restrict__ dst,
             int L, int R, int C, int dls, int dco)
{
    size_t total  = (size_t)L * R * C;
    size_t stride = (size_t)gridDim.x * 256;
    for (size_t i = (size_t)blockIdx.x * 256 + threadIdx.x; i < total; i += stride) {
        size_t rc  = (size_t)R * C;
        size_t l   = i / rc;
        size_t rem = i - l * rc;
        int r = (int)(rem / C);
        int c = (int)(rem - (size_t)r * C);
        dst[l * (size_t)dls + (size_t)(dco + c) * R + r] = f2bf(src[i]);
    }
}

// ---------------------------------------------------------------------------
// Embedding: x[row][c] = bf16(tok_emb[idx[row]][c] + pos_emb[row%256][c])
// grid*256 = 65536*48 (8-elem groups). Also zeroes the 32-entry loss buffer.
// ---------------------------------------------------------------------------
__global__ __launch_bounds__(256)
void embed_k(const int* __restrict__ idx, const float* __restrict__ tok,
             const float* __restrict__ pos, u16* __restrict__ x,
             float* __restrict__ lossbuf)
{
    if (blockIdx.x == 0 && threadIdx.x < 32) lossbuf[threadIdx.x] = 0.f;
    int gi  = blockIdx.x * 256 + threadIdx.x;
    int row = gi / 48;
    int cg  = gi - row * 48;
    int t   = row & 255;
    const float4* ta = (const float4*)(tok + (size_t)idx[row] * 384 + cg * 8);
    const float4* pa = (const float4*)(pos + (size_t)t * 384 + cg * 8);
    float4 a0 = ta[0], a1 = ta[1], p0 = pa[0], p1 = pa[1];
    u16 o[8] = { f2bf(a0.x+p0.x), f2bf(a0.y+p0.y), f2bf(a0.z+p0.z), f2bf(a0.w+p0.w),
                 f2bf(a1.x+p1.x), f2bf(a1.y+p1.y), f2bf(a1.z+p1.z), f2bf(a1.w+p1.w) };
    *(uint4*)(x + (size_t)row * 384 + cg * 8) = *(uint4*)o;
}

// ---------------------------------------------------------------------------
// LayerNorm over C=384 (bf16 in, bf16 out): one wave per row. grid = 65536/4
// ---------------------------------------------------------------------------
__global__ __launch_bounds__(256)
void ln_k(const u16* __restrict__ x, const float* __restrict__ gg,
          const float* __restrict__ bb, u16* __restrict__ out)
{
    const int lane = threadIdx.x & 63;
    const int w    = threadIdx.x >> 6;
    const size_t row = (size_t)blockIdx.x * 4 + w;
    const u32* xr = (const u32*)(x + row * 384);
    u32 d[3] = { xr[lane], xr[64 + lane], xr[128 + lane] };
    float v[6];
#pragma unroll
    for (int k = 0; k < 3; ++k) { v[2*k] = bflo(d[k]); v[2*k+1] = bfhi(d[k]); }
    float s = 0.f, sq = 0.f;
#pragma unroll
    for (int j = 0; j < 6; ++j) { s += v[j]; sq += v[j]*v[j]; }
#pragma unroll
    for (int m = 1; m < 64; m <<= 1) { s += __shfl_xor(s, m); sq += __shfl_xor(sq, m); }
    float mean = s * (1.f / 384.f);
    float var  = sq * (1.f / 384.f) - mean * mean;
    float rs   = rsqrtf(var + 1e-5f);
    u32* orow = (u32*)(out + row * 384);
#pragma unroll
    for (int k = 0; k < 3; ++k) {
        int c = k * 128 + 2 * lane;
        float o0 = (v[2*k]   - mean) * rs * gg[c]   + bb[c];
        float o1 = (v[2*k+1] - mean) * rs * gg[c+1] + bb[c+1];
        orow[k*64 + lane] = (u32)f2bf(o0) | ((u32)f2bf(o1) << 16);
    }
}

// ---------------------------------------------------------------------------
// GEMM: A[M,K] bf16 row-major x Bt[N,K] bf16 (pre-transposed) -> C [M,N]
// 128x128 tile, BK=32, 4 waves (2x2 of 64x64), mfma 16x16x32 bf16.
// global_load_lds(16B) staging, double-buffered, XOR-swizzle via pre-swizzled
// global source (T21).
// Grid is 1D (ntm*ntn blocks, multiple of 8). Block order: XCD-chunked
// (T1 swizzle) then A-panel-major (m = swz/ntn) -- B weights are L2-resident
// (<=1.2MB), so A streams from HBM exactly once.
// EPI: 0 = bf16 store, 1 = bias+relu bf16, 2 = bf16 residual rmw (+bias),
//      3 = f32 store (+bias), cols guarded to N (head logits)
// ---------------------------------------------------------------------------
template<int EPI>
__global__ __launch_bounds__(256)
void gemm_bt(const u16* __restrict__ A, const u16* __restrict__ Bt,
             u16* __restrict__ C, float* __restrict__ Cf,
             const float* __restrict__ bias, int K, int N)
{
    __shared__ u16 As[2][128*32];
    __shared__ u16 Bs[2][128*32];
    const int tid = threadIdx.x;
    const int lane = tid & 63;
    const int w  = tid >> 6;
    const int wm = w >> 1, wn = w & 1;

    // XCD-chunked, A-panel-major block decode
    const int ntn = (N + 127) >> 7;
    const int cpx = gridDim.x >> 3;                 // blocks per XCD chunk
    const int swz = (blockIdx.x & 7) * cpx + (blockIdx.x >> 3);
    const int mt  = swz / ntn;
    const int m0  = mt * 128;
    const int n0  = (swz - mt * ntn) * 128;

    const int g   = lane >> 4;
    const int l15 = lane & 15;

    f32x4 acc[4][4] = {};
    const int nk = K >> 5;

    auto stage = [&](int buf, int t) {
        const int k0 = t << 5;
#pragma unroll
        for (int c = 0; c < 2; ++c) {
            int i   = c * 256 + tid;
            int row = i >> 2;                       // 0..127
            int seg = (i & 3) ^ (row & 3);          // pre-swizzled source
            gld_lds16(A  + (size_t)(m0 + row) * K + k0 + seg * 8,
                      (char*)(&As[buf][0]) + (c * 256 + w * 64) * 16);
            gld_lds16(Bt + (size_t)(n0 + row) * K + k0 + seg * 8,
                      (char*)(&Bs[buf][0]) + (c * 256 + w * 64) * 16);
        }
    };

    stage(0, 0);
    __syncthreads();
    int cur = 0;
    for (int t = 0; t < nk; ++t) {
        if (t + 1 < nk) stage(cur ^ 1, t + 1);
        const char* Ab = (const char*)&As[cur][0];
        const char* Bb = (const char*)&Bs[cur][0];
        bf16x8 af[4], bfv[4];
#pragma unroll
        for (int fm = 0; fm < 4; ++fm) {
            int row = wm*64 + fm*16 + l15;
            af[fm] = *(const bf16x8*)(Ab + row*64 + ((g ^ (row & 3)) * 16));
        }
#pragma unroll
        for (int fn = 0; fn < 4; ++fn) {
            int row = wn*64 + fn*16 + l15;
            bfv[fn] = *(const bf16x8*)(Bb + row*64 + ((g ^ (row & 3)) * 16));
        }
#pragma unroll
        for (int fm = 0; fm < 4; ++fm)
#pragma unroll
            for (int fn = 0; fn < 4; ++fn)
                acc[fm][fn] = __builtin_amdgcn_mfma_f32_16x16x32_bf16(
                    af[fm], bfv[fn], acc[fm][fn], 0, 0, 0);
        __syncthreads();
        cur ^= 1;
    }

    // epilogue: D row = base + (lane>>4)*4 + r, col = base + (lane&15)
#pragma unroll
    for (int fm = 0; fm < 4; ++fm) {
        int rowb = m0 + wm*64 + fm*16 + g*4;
#pragma unroll
        for (int fn = 0; fn < 4; ++fn) {
            int col = n0 + wn*64 + fn*16 + l15;
            float bv = (EPI == 0) ? 0.f
                     : ((EPI == 3 && col >= N) ? 0.f : bias[col]);
#pragma unroll
            for (int r = 0; r < 4; ++r) {
                size_t off = (size_t)(rowb + r) * N + col;
                float vv = acc[fm][fn][r];
                if (EPI == 0) {
                    C[off] = f2bf(vv);
                } else if (EPI == 1) {
                    vv += bv; vv = vv > 0.f ? vv : 0.f;
                    C[off] = f2bf(vv);
                } else if (EPI == 2) {
                    C[off] = f2bf(bf2f(C[off]) + vv + bv);
                } else {
                    if (col < N) Cf[off] = vv + bv;
                }
            }
        }
    }
}

// ---------------------------------------------------------------------------
// Flash attention, one block per (b_local, h). qkv interleaved [row][1152].
// K [256][64], Vt [64][256], per-wave P [64][64] in LDS, XOR-swizzled.
// Online softmax, causal. O -> op rows [b*256+t][384].
// ---------------------------------------------------------------------------
__global__ __launch_bounds__(256)
void attn_k(const u16* __restrict__ qkv, u16* __restrict__ op)
{
    __shared__ u16 Ks[256*64];        // 32 KiB
    __shared__ u16 Vt[64*256];        // 32 KiB (transposed)
    __shared__ u16 Ps[4][64*64];      // 32 KiB (per-wave)
    const int tid  = threadIdx.x;
    const int lane = tid & 63;
    const int w    = tid >> 6;
    const int g    = lane >> 4;
    const int l15  = lane & 15;
    const int bh = blockIdx.x;
    const int b  = bh / 6, hh = bh - b * 6;
    const size_t baseQ = (size_t)b * 256 * 1152 + hh * 64;
    const size_t baseK = baseQ + 384;
    const size_t baseV = baseQ + 768;

#pragma unroll
    for (int cc = 0; cc < 8; ++cc) {
        int i    = cc * 256 + tid;
        int row  = i >> 3;
        int slot = (i & 7) ^ (row & 7);
        gld_lds16(qkv + baseK + (size_t)row * 1152 + slot * 8,
                  (char*)Ks + (cc * 256 + w * 64) * 16);
    }
#pragma unroll
    for (int it = 0; it < 16; ++it) {
        int j    = it * 256 + tid;
        int trow = j >> 4;
        int d0   = (j & 15) * 4;
        uint2 val = *(const uint2*)(qkv + baseV + (size_t)trow * 1152 + d0);
        u16 e0 = (u16)(val.x & 0xffff), e1 = (u16)(val.x >> 16);
        u16 e2 = (u16)(val.y & 0xffff), e3 = (u16)(val.y >> 16);
        *(u16*)((char*)Vt + (d0+0)*512 + ((trow*2) ^ (((d0+0)&7) << 4))) = e0;
        *(u16*)((char*)Vt + (d0+1)*512 + ((trow*2) ^ (((d0+1)&7) << 4))) = e1;
        *(u16*)((char*)Vt + (d0+2)*512 + ((trow*2) ^ (((d0+2)&7) << 4))) = e2;
        *(u16*)((char*)Vt + (d0+3)*512 + ((trow*2) ^ (((d0+3)&7) << 4))) = e3;
    }
    __syncthreads();

    const int r0 = w * 64;
    bf16x8 qf[4][2];
#pragma unroll
    for (int fm = 0; fm < 4; ++fm)
#pragma unroll
        for (int kk = 0; kk < 2; ++kk)
            qf[fm][kk] = *(const bf16x8*)(qkv + baseQ +
                (size_t)(r0 + fm*16 + l15) * 1152 + kk*32 + g*8);

    f32x4 oacc[4][4] = {};
    float mst[4][4], lst[4][4];
#pragma unroll
    for (int i = 0; i < 4; ++i)
#pragma unroll
        for (int r = 0; r < 4; ++r) { mst[i][r] = -1e30f; lst[i][r] = 0.f; }

    for (int kt = 0; kt <= w; ++kt) {
        f32x4 s[4][4] = {};
#pragma unroll
        for (int kk = 0; kk < 2; ++kk) {
            bf16x8 kf[4];
#pragma unroll
            for (int fn = 0; fn < 4; ++fn) {
                int row = kt*64 + fn*16 + l15;
                kf[fn] = *(const bf16x8*)((char*)Ks + row*128 +
                          ((kk*64 + g*16) ^ ((row & 7) << 4)));
            }
#pragma unroll
            for (int fm = 0; fm < 4; ++fm)
#pragma unroll
                for (int fn = 0; fn < 4; ++fn)
                    s[fm][fn] = __builtin_amdgcn_mfma_f32_16x16x32_bf16(
                        qf[fm][kk], kf[fn], s[fm][fn], 0, 0, 0);
        }
        const bool diag = (kt == w);
#pragma unroll
        for (int fm = 0; fm < 4; ++fm) {
#pragma unroll
            for (int r = 0; r < 4; ++r) {
                int rowg = r0 + fm*16 + g*4 + r;
                float mx = -1e30f;
#pragma unroll
                for (int fn = 0; fn < 4; ++fn) {
                    float val = s[fm][fn][r] * 0.125f;
                    if (diag) {
                        int colg = kt*64 + fn*16 + l15;
                        if (colg > rowg) val = -1e30f;
                    }
                    s[fm][fn][r] = val;
                    mx = fmaxf(mx, val);
                }
                mx = fmaxf(mx, __shfl_xor(mx, 1));
                mx = fmaxf(mx, __shfl_xor(mx, 2));
                mx = fmaxf(mx, __shfl_xor(mx, 4));
                mx = fmaxf(mx, __shfl_xor(mx, 8));
                float mnew = fmaxf(mst[fm][r], mx);
                float sf   = __expf(mst[fm][r] - mnew);
                mst[fm][r] = mnew;
                float rowsum = 0.f;
#pragma unroll
                for (int fn = 0; fn < 4; ++fn) {
                    float pe = __expf(s[fm][fn][r] - mnew);
                    s[fm][fn][r] = pe;
                    rowsum += pe;
                }
                rowsum += __shfl_xor(rowsum, 1);
                rowsum += __shfl_xor(rowsum, 2);
                rowsum += __shfl_xor(rowsum, 4);
                rowsum += __shfl_xor(rowsum, 8);
                lst[fm][r] = lst[fm][r] * sf + rowsum;
#pragma unroll
                for (int fd = 0; fd < 4; ++fd) oacc[fm][fd][r] *= sf;
                int prow = fm*16 + g*4 + r;
#pragma unroll
                for (int fn = 0; fn < 4; ++fn) {
                    int pcol = fn*16 + l15;
                    *(u16*)((char*)Ps[w] + prow*128 +
                            ((pcol*2) ^ ((prow & 7) << 4))) = f2bf(s[fm][fn][r]);
                }
            }
        }
        asm volatile("s_waitcnt lgkmcnt(0)" ::: "memory");
#pragma unroll
        for (int kk2 = 0; kk2 < 2; ++kk2) {
            bf16x8 pa[4], vb[4];
#pragma unroll
            for (int fm = 0; fm < 4; ++fm) {
                int prow = fm*16 + l15;
                pa[fm] = *(const bf16x8*)((char*)Ps[w] + prow*128 +
                          ((kk2*64 + g*16) ^ ((prow & 7) << 4)));
            }
#pragma unroll
            for (int fd = 0; fd < 4; ++fd) {
                int vrow = fd*16 + l15;
                vb[fd] = *(const bf16x8*)((char*)Vt + vrow*512 +
                          ((kt*128 + kk2*64 + g*16) ^ ((vrow & 7) << 4)));
            }
#pragma unroll
            for (int fm = 0; fm < 4; ++fm)
#pragma unroll
                for (int fd = 0; fd < 4; ++fd)
                    oacc[fm][fd] = __builtin_amdgcn_mfma_f32_16x16x32_bf16(
                        pa[fm], vb[fd], oacc[fm][fd], 0, 0, 0);
        }
    }
#pragma unroll
    for (int fm = 0; fm < 4; ++fm)
#pragma unroll
        for (int r = 0; r < 4; ++r) {
            int rowg = r0 + fm*16 + g*4 + r;
            float inv = 1.f / lst[fm][r];
#pragma unroll
            for (int fd = 0; fd < 4; ++fd)
                op[((size_t)b * 256 + rowg) * 384 + hh*64 + fd*16 + l15] =
                    f2bf(oacc[fm][fd][r] * inv);
        }
}

// ---------------------------------------------------------------------------
// Loss from f32 logits [65536][65]: 1024 blocks x 4 waves, 16 rows per wave,
// local accumulation, ONE atomic per block (kills cross-XCD atomic serialize).
// ---------------------------------------------------------------------------
__global__ __launch_bounds__(256)
void loss_k(const float* __restrict__ logits, const int* __restrict__ tgt,
            float* __restrict__ lossbuf)
{
    __shared__ float wloss[4];
    const int lane = threadIdx.x & 63;
    const int w    = threadIdx.x >> 6;
    const int wid  = blockIdx.x * 4 + w;          // 0..4095
    float acc = 0.f;
    for (int rr = 0; rr < 16; ++rr) {
        const size_t row = (size_t)wid * 16 + rr;
        const float* lr = logits + row * 65;
        float v   = lr[lane];
        float l64 = lr[64];
        float mx = fmaxf(v, l64);
#pragma unroll
        for (int m = 1; m < 64; m <<= 1) mx = fmaxf(mx, __shfl_xor(mx, m));
        float e = __expf(v - mx);
#pragma unroll
        for (int m = 1; m < 64; m <<= 1) e += __shfl_xor(e, m);
        e += __expf(l64 - mx);
        float lse = mx + logf(e);
        int t = tgt[row];
        float lt0 = __shfl(v, t < 64 ? t : 0);
        float lt  = (t < 64) ? lt0 : l64;
        acc += lse - lt;                           // lane-uniform
    }
    if (lane == 0) wloss[w] = acc;
    __syncthreads();
    if (threadIdx.x == 0) {
        float bsum = wloss[0] + wloss[1] + wloss[2] + wloss[3];
        atomicAdd(&lossbuf[blockIdx.x & 31], bsum * (1.f / 65536.f));
    }
}

__global__ void loss_finish_k(const float* __restrict__ part, float* __restrict__ outp)
{
    int lane = threadIdx.x;
    float v = (lane < 32) ? part[lane] : 0.f;
#pragma unroll
    for (int m = 1; m < 64; m <<= 1) v += __shfl_xor(v, m);
    if (lane == 0) outp[0] = v;
}

// ---------------------------------------------------------------------------
extern "C" void kernel_launch(void* const* d_in, const int* in_sizes, int n_in,
                              void* d_out, int out_size, void* d_ws, size_t ws_size,
                              hipStream_t stream)
{
    (void)in_sizes; (void)n_in; (void)out_size;
    const int*   idx  = (const int*)d_in[0];
    const int*   tgt  = (const int*)d_in[1];
    const float* tok  = (const float*)d_in[2];
    const float* pos  = (const float*)d_in[3];
    const float* Wq   = (const float*)d_in[4];
    const float* Wk   = (const float*)d_in[5];
    const float* Wv   = (const float*)d_in[6];
    const float* Wo   = (const float*)d_in[7];
    const float* bo   = (const float*)d_in[8];
    const float* ln1g = (const float*)d_in[9];
    const float* ln1b = (const float*)d_in[10];
    const float* ln2g = (const float*)d_in[11];
    const float* ln2b = (const float*)d_in[12];
    const float* W1   = (const float*)d_in[13];
    const float* b1   = (const float*)d_in[14];
    const float* W2   = (const float*)d_in[15];
    const float* b2   = (const float*)d_in[16];
    const float* lnfg = (const float*)d_in[17];
    const float* lnfb = (const float*)d_in[18];
    const float* Wh   = (const float*)d_in[19];
    const float* bh   = (const float*)d_in[20];

    // ---- adaptive chunk count based on ws_size ----
    const size_t fixed = (size_t)65536*384*2 * 2        // x + hbuf
                       + (size_t)6*1152*384*2           // wqkv
                       + (size_t)6*384*384*2            // wto
                       + (size_t)6*1536*384*2 * 2       // wt1 + wt2
                       + (size_t)128*384*2 + 4096;      // wth (padded) + loss/slack
    int NC = 4;
    if      (ws_size >= fixed + (size_t)65536*1536*2)      NC = 1;
    else if (ws_size >= fixed + (size_t)32768*1536*2)      NC = 2;
    const int CR = 65536 / NC;                           // rows per chunk

    // ---- workspace layout ----
    char* p = (char*)d_ws;
    u16* x    = (u16*)p;  p += (size_t)65536*384*2;      // residual bf16
    u16* hbuf = (u16*)p;  p += (size_t)65536*384*2;      // LN out / attn O
    u16* r1   = (u16*)p;  p += (size_t)CR*1536*2;        // qkv / ff chunk
    u16* wqkv = (u16*)p;  p += (size_t)6*1152*384*2;     // [L][1152][384]
    u16* wto  = (u16*)p;  p += (size_t)6*384*384*2;      // [L][384][384]
    u16* wt1  = (u16*)p;  p += (size_t)6*1536*384*2;     // [L][1536][384]
    u16* wt2  = (u16*)p;  p += (size_t)6*384*1536*2;     // [L][384][1536]
    u16* wth  = (u16*)p;  p += (size_t)128*384*2;        // [65->128 pad][384]
    float* lossbuf = (float*)p;                          // 32 f32 partials

    float* out   = (float*)d_out;
    float* lossp = out + (size_t)65536 * 65;

    // ---- weight prep (bf16, transposed to [N][K]) ----
    convT_k<<<1024, 256, 0, stream>>>(Wq, wqkv, 6, 384, 384, 442368, 0);
    convT_k<<<1024, 256, 0, stream>>>(Wk, wqkv, 6, 384, 384, 442368, 384);
    convT_k<<<1024, 256, 0, stream>>>(Wv, wqkv, 6, 384, 384, 442368, 768);
    convT_k<<<1024, 256, 0, stream>>>(Wo, wto, 6, 384, 384, 147456, 0);
    convT_k<<<2048, 256, 0, stream>>>(W1, wt1, 6, 384, 1536, 589824, 0);
    convT_k<<<2048, 256, 0, stream>>>(W2, wt2, 6, 1536, 384, 589824, 0);
    convT_k<<<64,   256, 0, stream>>>(Wh, wth, 1, 384, 65, 24960, 0);

    embed_k<<<12288, 256, 0, stream>>>(idx, tok, pos, x, lossbuf);

    for (int l = 0; l < 6; ++l) {
        ln_k<<<16384, 256, 0, stream>>>(x, ln1g + l*384, ln1b + l*384, hbuf);
        for (int ac = 0; ac < NC; ++ac) {
            const size_t ro = (size_t)ac * CR;
            gemm_bt<0><<<dim3((CR/128)*9), 256, 0, stream>>>(
                hbuf + ro*384, wqkv + (size_t)l*442368, r1, nullptr, nullptr, 384, 1152);
            attn_k<<<(CR/256)*6, 256, 0, stream>>>(r1, hbuf + ro*384);
        }
        gemm_bt<2><<<dim3(512*3), 256, 0, stream>>>(
            hbuf, wto + (size_t)l*147456, x, nullptr, bo + l*384, 384, 384);
        ln_k<<<16384, 256, 0, stream>>>(x, ln2g + l*384, ln2b + l*384, hbuf);
        for (int mc = 0; mc < NC; ++mc) {
            const size_t ro = (size_t)mc * CR;
            gemm_bt<1><<<dim3((CR/128)*12), 256, 0, stream>>>(
                hbuf + ro*384, wt1 + (size_t)l*589824, r1, nullptr, b1 + l*1536, 384, 1536);
            gemm_bt<2><<<dim3((CR/128)*3), 256, 0, stream>>>(
                r1, wt2 + (size_t)l*589824, x + ro*384, nullptr, b2 + l*384, 1536, 384);
        }
    }
    ln_k<<<16384, 256, 0, stream>>>(x, lnfg, lnfb, hbuf);
    // head: logits (f32, +bias) straight to d_out via MFMA GEMM, cols<65
    gemm_bt<3><<<dim3(512), 256, 0, stream>>>(
        hbuf, wth, nullptr, out, bh, 384, 65);
    loss_k<<<1024, 256, 0, stream>>>(out, tgt, lossbuf);
    loss_finish_k<<<1, 64, 0, stream>>>(lossbuf, lossp);
}

// Round 11
// 3349.507 us; speedup vs baseline: 1.4924x; 1.1461x over previous
//
#include <hip/hip_runtime.h>
#include <stdint.h>

// ---------------------------------------------------------------------------
// NanoGPT forward (L=6,H=6,C=384,T=256,V=65,B=256) on gfx950.
// Residual x in bf16; GEMMs bf16 MFMA (f32 accum); flash attention per (b,h).
// GEMM grid: A-panel-major + XCD-chunk swizzle (weights are L2-resident).
// attn: 8 waves/block (2/SIMD), balanced causal pairing, conflict-free Vt.
// ---------------------------------------------------------------------------

typedef unsigned short u16;
typedef unsigned int   u32;
typedef __attribute__((ext_vector_type(8))) short bf16x8;   // 8 bf16 (4 VGPR)
typedef __attribute__((ext_vector_type(4))) float f32x4;    // MFMA accumulator

typedef const __attribute__((address_space(1))) void* gas_ptr;
typedef __attribute__((address_space(3))) void* lds_ptr;

__device__ __forceinline__ void gld_lds16(const void* g, void* l) {
    __builtin_amdgcn_global_load_lds((gas_ptr)g, (lds_ptr)l, 16, 0, 0);
}

__device__ __forceinline__ u16 f2bf(float f) {          // RNE f32->bf16
    u32 u = __builtin_bit_cast(u32, f);
    u = u + 0x7fffu + ((u >> 16) & 1u);
    return (u16)(u >> 16);
}
__device__ __forceinline__ float bf2f(u16 h) { return __builtin_bit_cast(float, (u32)h << 16); }
__device__ __forceinline__ float bflo(u32 u) { return __builtin_bit_cast(float, u << 16); }
__device__ __forceinline__ float bfhi(u32 u) { return __builtin_bit_cast(float, u & 0xffff0000u); }

// ---------------------------------------------------------------------------
// Convert+transpose: src f32 [L][R][C] -> dst bf16, dst[l*dls + (dco+c)*R + r]
// ---------------------------------------------------------------------------
__global__ __launch_bounds__(256)
void convT_k(const float* __restrict__ src, u16* __restrict__ dst,
             int L, int R, int C, int dls, int dco)
{
    size_t total  = (size_t)L * R * C;
    size_t stride = (size_t)gridDim.x * 256;
    for (size_t i = (size_t)blockIdx.x * 256 + threadIdx.x; i < total; i += stride) {
        size_t rc  = (size_t)R * C;
        size_t l   = i / rc;
        size_t rem = i - l * rc;
        int r = (int)(rem / C);
        int c = (int)(rem - (size_t)r * C);
        dst[l * (size_t)dls + (size_t)(dco + c) * R + r] = f2bf(src[i]);
    }
}

// ---------------------------------------------------------------------------
// Embedding: x[row][c] = bf16(tok_emb[idx[row]][c] + pos_emb[row%256][c])
// ---------------------------------------------------------------------------
__global__ __launch_bounds__(256)
void embed_k(const int* __restrict__ idx, const float* __restrict__ tok,
             const float* __restrict__ pos, u16* __restrict__ x,
             float* __restrict__ lossbuf)
{
    if (blockIdx.x == 0 && threadIdx.x < 32) lossbuf[threadIdx.x] = 0.f;
    int gi  = blockIdx.x * 256 + threadIdx.x;
    int row = gi / 48;
    int cg  = gi - row * 48;
    int t   = row & 255;
    const float4* ta = (const float4*)(tok + (size_t)idx[row] * 384 + cg * 8);
    const float4* pa = (const float4*)(pos + (size_t)t * 384 + cg * 8);
    float4 a0 = ta[0], a1 = ta[1], p0 = pa[0], p1 = pa[1];
    u16 o[8] = { f2bf(a0.x+p0.x), f2bf(a0.y+p0.y), f2bf(a0.z+p0.z), f2bf(a0.w+p0.w),
                 f2bf(a1.x+p1.x), f2bf(a1.y+p1.y), f2bf(a1.z+p1.z), f2bf(a1.w+p1.w) };
    *(uint4*)(x + (size_t)row * 384 + cg * 8) = *(uint4*)o;
}

// ---------------------------------------------------------------------------
// LayerNorm over C=384 (bf16 in, bf16 out): one wave per row. grid = 65536/4
// ---------------------------------------------------------------------------
__global__ __launch_bounds__(256)
void ln_k(const u16* __restrict__ x, const float* __restrict__ gg,
          const float* __restrict__ bb, u16* __restrict__ out)
{
    const int lane = threadIdx.x & 63;
    const int w    = threadIdx.x >> 6;
    const size_t row = (size_t)blockIdx.x * 4 + w;
    const u32* xr = (const u32*)(x + row * 384);
    u32 d[3] = { xr[lane], xr[64 + lane], xr[128 + lane] };
    float v[6];
#pragma unroll
    for (int k = 0; k < 3; ++k) { v[2*k] = bflo(d[k]); v[2*k+1] = bfhi(d[k]); }
    float s = 0.f, sq = 0.f;
#pragma unroll
    for (int j = 0; j < 6; ++j) { s += v[j]; sq += v[j]*v[j]; }
#pragma unroll
    for (int m = 1; m < 64; m <<= 1) { s += __shfl_xor(s, m); sq += __shfl_xor(sq, m); }
    float mean = s * (1.f / 384.f);
    float var  = sq * (1.f / 384.f) - mean * mean;
    float rs   = rsqrtf(var + 1e-5f);
    u32* orow = (u32*)(out + row * 384);
#pragma unroll
    for (int k = 0; k < 3; ++k) {
        int c = k * 128 + 2 * lane;
        float o0 = (v[2*k]   - mean) * rs * gg[c]   + bb[c];
        float o1 = (v[2*k+1] - mean) * rs * gg[c+1] + bb[c+1];
        orow[k*64 + lane] = (u32)f2bf(o0) | ((u32)f2bf(o1) << 16);
    }
}

// ---------------------------------------------------------------------------
// GEMM: A[M,K] bf16 row-major x Bt[N,K] bf16 (pre-transposed) -> C [M,N]
// 128x128 tile, BK=32, 4 waves, mfma 16x16x32 bf16. 1D grid, XCD-chunked +
// A-panel-major decode. EPI: 0 store, 1 bias+relu, 2 residual rmw, 3 f32 head.
// ---------------------------------------------------------------------------
template<int EPI>
__global__ __launch_bounds__(256)
void gemm_bt(const u16* __restrict__ A, const u16* __restrict__ Bt,
             u16* __restrict__ C, float* __restrict__ Cf,
             const float* __restrict__ bias, int K, int N)
{
    __shared__ u16 As[2][128*32];
    __shared__ u16 Bs[2][128*32];
    const int tid = threadIdx.x;
    const int lane = tid & 63;
    const int w  = tid >> 6;
    const int wm = w >> 1, wn = w & 1;

    const int ntn = (N + 127) >> 7;
    const int cpx = gridDim.x >> 3;                 // blocks per XCD chunk
    const int swz = (blockIdx.x & 7) * cpx + (blockIdx.x >> 3);
    const int mt  = swz / ntn;
    const int m0  = mt * 128;
    const int n0  = (swz - mt * ntn) * 128;

    const int g   = lane >> 4;
    const int l15 = lane & 15;

    f32x4 acc[4][4] = {};
    const int nk = K >> 5;

    auto stage = [&](int buf, int t) {
        const int k0 = t << 5;
#pragma unroll
        for (int c = 0; c < 2; ++c) {
            int i   = c * 256 + tid;
            int row = i >> 2;
            int seg = (i & 3) ^ (row & 3);          // pre-swizzled source
            gld_lds16(A  + (size_t)(m0 + row) * K + k0 + seg * 8,
                      (char*)(&As[buf][0]) + (c * 256 + w * 64) * 16);
            gld_lds16(Bt + (size_t)(n0 + row) * K + k0 + seg * 8,
                      (char*)(&Bs[buf][0]) + (c * 256 + w * 64) * 16);
        }
    };

    stage(0, 0);
    __syncthreads();
    int cur = 0;
    for (int t = 0; t < nk; ++t) {
        if (t + 1 < nk) stage(cur ^ 1, t + 1);
        const char* Ab = (const char*)&As[cur][0];
        const char* Bb = (const char*)&Bs[cur][0];
        bf16x8 af[4], bfv[4];
#pragma unroll
        for (int fm = 0; fm < 4; ++fm) {
            int row = wm*64 + fm*16 + l15;
            af[fm] = *(const bf16x8*)(Ab + row*64 + ((g ^ (row & 3)) * 16));
        }
#pragma unroll
        for (int fn = 0; fn < 4; ++fn) {
            int row = wn*64 + fn*16 + l15;
            bfv[fn] = *(const bf16x8*)(Bb + row*64 + ((g ^ (row & 3)) * 16));
        }
#pragma unroll
        for (int fm = 0; fm < 4; ++fm)
#pragma unroll
            for (int fn = 0; fn < 4; ++fn)
                acc[fm][fn] = __builtin_amdgcn_mfma_f32_16x16x32_bf16(
                    af[fm], bfv[fn], acc[fm][fn], 0, 0, 0);
        __syncthreads();
        cur ^= 1;
    }

#pragma unroll
    for (int fm = 0; fm < 4; ++fm) {
        int rowb = m0 + wm*64 + fm*16 + g*4;
#pragma unroll
        for (int fn = 0; fn < 4; ++fn) {
            int col = n0 + wn*64 + fn*16 + l15;
            float bv = (EPI == 0) ? 0.f
                     : ((EPI == 3 && col >= N) ? 0.f : bias[col]);
#pragma unroll
            for (int r = 0; r < 4; ++r) {
                size_t off = (size_t)(rowb + r) * N + col;
                float vv = acc[fm][fn][r];
                if (EPI == 0) {
                    C[off] = f2bf(vv);
                } else if (EPI == 1) {
                    vv += bv; vv = vv > 0.f ? vv : 0.f;
                    C[off] = f2bf(vv);
                } else if (EPI == 2) {
                    C[off] = f2bf(bf2f(C[off]) + vv + bv);
                } else {
                    if (col < N) Cf[off] = vv + bv;
                }
            }
        }
    }
}

// ---------------------------------------------------------------------------
// Flash attention, one block per (b_local, h). qkv interleaved [row][1152].
// 8 waves x 512 threads; wave w owns Q-row block rb = (w<4 ? w : 11-w)*32
// (pairs (1,4),(1,4),(2,3),(2,3) kt-tiles per SIMD -> perfectly balanced).
// LDS: Ks [256][64] XOR-swizzled (gld_lds16); Vt [64 d][264 t] padded stride
// (528B, 2-way banks, no swizzle); Ps per-wave [32][72] (144B stride).
// Online softmax, causal. O -> op rows [b*256+t][384].
// ---------------------------------------------------------------------------
__global__ __launch_bounds__(512, 2)
void attn_k(const u16* __restrict__ qkv, u16* __restrict__ op)
{
    __shared__ u16 Ks[256*64];        // 32 KiB
    __shared__ u16 Vt[64*264];        // 33 KiB (transposed, padded stride)
    __shared__ u16 Ps[8][32*72];      // 36 KiB (per-wave, padded stride)
    const int tid  = threadIdx.x;
    const int lane = tid & 63;
    const int w    = tid >> 6;        // 0..7
    const int g    = lane >> 4;
    const int l15  = lane & 15;
    const int bh = blockIdx.x;
    const int b  = bh / 6, hh = bh - b * 6;
    const size_t baseQ = (size_t)b * 256 * 1152 + hh * 64;
    const size_t baseK = baseQ + 384;
    const size_t baseV = baseQ + 768;

    // stage K via global_load_lds, pre-swizzled source (8 slots/row of 16B)
#pragma unroll
    for (int cc = 0; cc < 4; ++cc) {
        int i    = cc * 512 + tid;            // 0..2047 chunks
        int row  = i >> 3;
        int slot = (i & 7) ^ (row & 7);
        gld_lds16(qkv + baseK + (size_t)row * 1152 + slot * 8,
                  (char*)Ks + (cc * 512 + w * 64) * 16);
    }
    // stage V transposed: lane q=tid&15 writes d in {q,q+16,q+32,q+48} at col t.
    // write bank = (4q + t/2)%32 -> 2-way (free). reads 32B-coalesced per group.
#pragma unroll
    for (int it = 0; it < 8; ++it) {
        int j = it * 512 + tid;               // 0..4095
        int q = j & 15;
        int t = j >> 4;                        // 0..255
        const u16* vrow = qkv + baseV + (size_t)t * 1152;
#pragma unroll
        for (int m = 0; m < 4; ++m) {
            int d = q + 16 * m;
            *(u16*)((char*)Vt + d * 528 + t * 2) = vrow[d];
        }
    }
    __syncthreads();

    const int rb = (w < 4) ? w : 11 - w;      // balanced causal pairing
    const int r0 = rb * 32;
    const int ktmax = rb >> 1;

    bf16x8 qf[2][2];
#pragma unroll
    for (int fm = 0; fm < 2; ++fm)
#pragma unroll
        for (int kk = 0; kk < 2; ++kk)
            qf[fm][kk] = *(const bf16x8*)(qkv + baseQ +
                (size_t)(r0 + fm*16 + l15) * 1152 + kk*32 + g*8);

    f32x4 oacc[2][4] = {};
    float mst[2][4], lst[2][4];
#pragma unroll
    for (int i = 0; i < 2; ++i)
#pragma unroll
        for (int r = 0; r < 4; ++r) { mst[i][r] = -1e30f; lst[i][r] = 0.f; }

    char* Pw = (char*)Ps[w];

    for (int kt = 0; kt <= ktmax; ++kt) {
        f32x4 s[2][4] = {};
#pragma unroll
        for (int kk = 0; kk < 2; ++kk) {
            bf16x8 kf[4];
#pragma unroll
            for (int fn = 0; fn < 4; ++fn) {
                int row = kt*64 + fn*16 + l15;
                kf[fn] = *(const bf16x8*)((char*)Ks + row*128 +
                          ((kk*64 + g*16) ^ ((row & 7) << 4)));
            }
#pragma unroll
            for (int fm = 0; fm < 2; ++fm)
#pragma unroll
                for (int fn = 0; fn < 4; ++fn)
                    s[fm][fn] = __builtin_amdgcn_mfma_f32_16x16x32_bf16(
                        qf[fm][kk], kf[fn], s[fm][fn], 0, 0, 0);
        }
        const bool diag = (kt == ktmax);
#pragma unroll
        for (int fm = 0; fm < 2; ++fm) {
#pragma unroll
            for (int r = 0; r < 4; ++r) {
                int rowg = r0 + fm*16 + g*4 + r;
                float mx = -1e30f;
#pragma unroll
                for (int fn = 0; fn < 4; ++fn) {
                    float val = s[fm][fn][r] * 0.125f;
                    if (diag) {
                        int colg = kt*64 + fn*16 + l15;
                        if (colg > rowg) val = -1e30f;
                    }
                    s[fm][fn][r] = val;
                    mx = fmaxf(mx, val);
                }
                mx = fmaxf(mx, __shfl_xor(mx, 1));
                mx = fmaxf(mx, __shfl_xor(mx, 2));
                mx = fmaxf(mx, __shfl_xor(mx, 4));
                mx = fmaxf(mx, __shfl_xor(mx, 8));
                float mnew = fmaxf(mst[fm][r], mx);
                float sf   = __expf(mst[fm][r] - mnew);
                mst[fm][r] = mnew;
                float rowsum = 0.f;
#pragma unroll
                for (int fn = 0; fn < 4; ++fn) {
                    float pe = __expf(s[fm][fn][r] - mnew);
                    s[fm][fn][r] = pe;
                    rowsum += pe;
                }
                rowsum += __shfl_xor(rowsum, 1);
                rowsum += __shfl_xor(rowsum, 2);
                rowsum += __shfl_xor(rowsum, 4);
                rowsum += __shfl_xor(rowsum, 8);
                lst[fm][r] = lst[fm][r] * sf + rowsum;
#pragma unroll
                for (int fd = 0; fd < 4; ++fd) oacc[fm][fd][r] *= sf;
                int prow = fm*16 + g*4 + r;
#pragma unroll
                for (int fn = 0; fn < 4; ++fn) {
                    int pcol = fn*16 + l15;
                    *(u16*)(Pw + prow*144 + pcol*2) = f2bf(s[fm][fn][r]);
                }
            }
        }
        asm volatile("s_waitcnt lgkmcnt(0)" ::: "memory");  // P visible to own wave
#pragma unroll
        for (int kk2 = 0; kk2 < 2; ++kk2) {
            bf16x8 pa[2], vb[4];
#pragma unroll
            for (int fm = 0; fm < 2; ++fm) {
                int prow = fm*16 + l15;
                pa[fm] = *(const bf16x8*)(Pw + prow*144 + kk2*64 + g*16);
            }
#pragma unroll
            for (int fd = 0; fd < 4; ++fd) {
                int vrow = fd*16 + l15;
                vb[fd] = *(const bf16x8*)((char*)Vt + vrow*528 +
                          kt*128 + kk2*64 + g*16);
            }
#pragma unroll
            for (int fm = 0; fm < 2; ++fm)
#pragma unroll
                for (int fd = 0; fd < 4; ++fd)
                    oacc[fm][fd] = __builtin_amdgcn_mfma_f32_16x16x32_bf16(
                        pa[fm], vb[fd], oacc[fm][fd], 0, 0, 0);
        }
    }
#pragma unroll
    for (int fm = 0; fm < 2; ++fm)
#pragma unroll
        for (int r = 0; r < 4; ++r) {
            int rowg = r0 + fm*16 + g*4 + r;
            float inv = 1.f / lst[fm][r];
#pragma unroll
            for (int fd = 0; fd < 4; ++fd)
                op[((size_t)b * 256 + rowg) * 384 + hh*64 + fd*16 + l15] =
                    f2bf(oacc[fm][fd][r] * inv);
        }
}

// ---------------------------------------------------------------------------
// Loss from f32 logits [65536][65]: 1024 blocks x 4 waves, 16 rows per wave,
// local accumulation, ONE atomic per block.
// ---------------------------------------------------------------------------
__global__ __launch_bounds__(256)
void loss_k(const float* __restrict__ logits, const int* __restrict__ tgt,
            float* __restrict__ lossbuf)
{
    __shared__ float wloss[4];
    const int lane = threadIdx.x & 63;
    const int w    = threadIdx.x >> 6;
    const int wid  = blockIdx.x * 4 + w;          // 0..4095
    float acc = 0.f;
    for (int rr = 0; rr < 16; ++rr) {
        const size_t row = (size_t)wid * 16 + rr;
        const float* lr = logits + row * 65;
        float v   = lr[lane];
        float l64 = lr[64];
        float mx = fmaxf(v, l64);
#pragma unroll
        for (int m = 1; m < 64; m <<= 1) mx = fmaxf(mx, __shfl_xor(mx, m));
        float e = __expf(v - mx);
#pragma unroll
        for (int m = 1; m < 64; m <<= 1) e += __shfl_xor(e, m);
        e += __expf(l64 - mx);
        float lse = mx + logf(e);
        int t = tgt[row];
        float lt0 = __shfl(v, t < 64 ? t : 0);
        float lt  = (t < 64) ? lt0 : l64;
        acc += lse - lt;                           // lane-uniform
    }
    if (lane == 0) wloss[w] = acc;
    __syncthreads();
    if (threadIdx.x == 0) {
        float bsum = wloss[0] + wloss[1] + wloss[2] + wloss[3];
        atomicAdd(&lossbuf[blockIdx.x & 31], bsum * (1.f / 65536.f));
    }
}

__global__ void loss_finish_k(const float* __restrict__ part, float* __restrict__ outp)
{
    int lane = threadIdx.x;
    float v = (lane < 32) ? part[lane] : 0.f;
#pragma unroll
    for (int m = 1; m < 64; m <<= 1) v += __shfl_xor(v, m);
    if (lane == 0) outp[0] = v;
}

// ---------------------------------------------------------------------------
extern "C" void kernel_launch(void* const* d_in, const int* in_sizes, int n_in,
                              void* d_out, int out_size, void* d_ws, size_t ws_size,
                              hipStream_t stream)
{
    (void)in_sizes; (void)n_in; (void)out_size;
    const int*   idx  = (const int*)d_in[0];
    const int*   tgt  = (const int*)d_in[1];
    const float* tok  = (const float*)d_in[2];
    const float* pos  = (const float*)d_in[3];
    const float* Wq   = (const float*)d_in[4];
    const float* Wk   = (const float*)d_in[5];
    const float* Wv   = (const float*)d_in[6];
    const float* Wo   = (const float*)d_in[7];
    const float* bo   = (const float*)d_in[8];
    const float* ln1g = (const float*)d_in[9];
    const float* ln1b = (const float*)d_in[10];
    const float* ln2g = (const float*)d_in[11];
    const float* ln2b = (const float*)d_in[12];
    const float* W1   = (const float*)d_in[13];
    const float* b1   = (const float*)d_in[14];
    const float* W2   = (const float*)d_in[15];
    const float* b2   = (const float*)d_in[16];
    const float* lnfg = (const float*)d_in[17];
    const float* lnfb = (const float*)d_in[18];
    const float* Wh   = (const float*)d_in[19];
    const float* bh   = (const float*)d_in[20];

    // ---- adaptive chunk count based on ws_size ----
    const size_t fixed = (size_t)65536*384*2 * 2        // x + hbuf
                       + (size_t)6*1152*384*2           // wqkv
                       + (size_t)6*384*384*2            // wto
                       + (size_t)6*1536*384*2 * 2       // wt1 + wt2
                       + (size_t)128*384*2 + 4096;      // wth (padded) + loss/slack
    int NC = 4;
    if      (ws_size >= fixed + (size_t)65536*1536*2)      NC = 1;
    else if (ws_size >= fixed + (size_t)32768*1536*2)      NC = 2;
    const int CR = 65536 / NC;                           // rows per chunk

    // ---- workspace layout ----
    char* p = (char*)d_ws;
    u16* x    = (u16*)p;  p += (size_t)65536*384*2;      // residual bf16
    u16* hbuf = (u16*)p;  p += (size_t)65536*384*2;      // LN out / attn O
    u16* r1   = (u16*)p;  p += (size_t)CR*1536*2;        // qkv / ff chunk
    u16* wqkv = (u16*)p;  p += (size_t)6*1152*384*2;     // [L][1152][384]
    u16* wto  = (u16*)p;  p += (size_t)6*384*384*2;      // [L][384][384]
    u16* wt1  = (u16*)p;  p += (size_t)6*1536*384*2;     // [L][1536][384]
    u16* wt2  = (u16*)p;  p += (size_t)6*384*1536*2;     // [L][384][1536]
    u16* wth  = (u16*)p;  p += (size_t)128*384*2;        // [65->128 pad][384]
    float* lossbuf = (float*)p;                          // 32 f32 partials

    float* out   = (float*)d_out;
    float* lossp = out + (size_t)65536 * 65;

    // ---- weight prep (bf16, transposed to [N][K]) ----
    convT_k<<<1024, 256, 0, stream>>>(Wq, wqkv, 6, 384, 384, 442368, 0);
    convT_k<<<1024, 256, 0, stream>>>(Wk, wqkv, 6, 384, 384, 442368, 384);
    convT_k<<<1024, 256, 0, stream>>>(Wv, wqkv, 6, 384, 384, 442368, 768);
    convT_k<<<1024, 256, 0, stream>>>(Wo, wto, 6, 384, 384, 147456, 0);
    convT_k<<<2048, 256, 0, stream>>>(W1, wt1, 6, 384, 1536, 589824, 0);
    convT_k<<<2048, 256, 0, stream>>>(W2, wt2, 6, 1536, 384, 589824, 0);
    convT_k<<<64,   256, 0, stream>>>(Wh, wth, 1, 384, 65, 24960, 0);

    embed_k<<<12288, 256, 0, stream>>>(idx, tok, pos, x, lossbuf);

    for (int l = 0; l < 6; ++l) {
        ln_k<<<16384, 256, 0, stream>>>(x, ln1g + l*384, ln1b + l*384, hbuf);
        for (int ac = 0; ac < NC; ++ac) {
            const size_t ro = (size_t)ac * CR;
            gemm_bt<0><<<dim3((CR/128)*9), 256, 0, stream>>>(
                hbuf + ro*384, wqkv + (size_t)l*442368, r1, nullptr, nullptr, 384, 1152);
            attn_k<<<(CR/256)*6, 512, 0, stream>>>(r1, hbuf + ro*384);
        }
        gemm_bt<2><<<dim3(512*3), 256, 0, stream>>>(
            hbuf, wto + (size_t)l*147456, x, nullptr, bo + l*384, 384, 384);
        ln_k<<<16384, 256, 0, stream>>>(x, ln2g + l*384, ln2b + l*384, hbuf);
        for (int mc = 0; mc < NC; ++mc) {
            const size_t ro = (size_t)mc * CR;
            gemm_bt<1><<<dim3((CR/128)*12), 256, 0, stream>>>(
                hbuf + ro*384, wt1 + (size_t)l*589824, r1, nullptr, b1 + l*1536, 384, 1536);
            gemm_bt<2><<<dim3((CR/128)*3), 256, 0, stream>>>(
                r1, wt2 + (size_t)l*589824, x + ro*384, nullptr, b2 + l*384, 1536, 384);
        }
    }
    ln_k<<<16384, 256, 0, stream>>>(x, lnfg, lnfb, hbuf);
    // head: logits (f32, +bias) straight to d_out via MFMA GEMM, cols<65
    gemm_bt<3><<<dim3(512), 256, 0, stream>>>(
        hbuf, wth, nullptr, out, bh, 384, 65);
    loss_k<<<1024, 256, 0, stream>>>(out, tgt, lossbuf);
    loss_finish_k<<<1, 64, 0, stream>>>(lossbuf, lossp);
}

// Round 12
// 3340.694 us; speedup vs baseline: 1.4963x; 1.0026x over previous
//
#include <hip/hip_runtime.h>
#include <stdint.h>

// ---------------------------------------------------------------------------
// NanoGPT forward (L=6,H=6,C=384,T=256,V=65,B=256) on gfx950.
// Residual x in bf16; GEMMs bf16 MFMA (f32 accum); flash attention per (b,h).
// GEMM grid: A-panel-major + XCD-chunk swizzle (weights are L2-resident).
// GEMM LDS swizzle f(row)=(row>>1)&3 -> 2-way banks on ds_read_b128 (free).
// attn: 8 waves/block (2/SIMD), balanced causal pairing, conflict-free Vt.
// ---------------------------------------------------------------------------

typedef unsigned short u16;
typedef unsigned int   u32;
typedef __attribute__((ext_vector_type(8))) short bf16x8;   // 8 bf16 (4 VGPR)
typedef __attribute__((ext_vector_type(4))) float f32x4;    // MFMA accumulator

typedef const __attribute__((address_space(1))) void* gas_ptr;
typedef __attribute__((address_space(3))) void* lds_ptr;

__device__ __forceinline__ void gld_lds16(const void* g, void* l) {
    __builtin_amdgcn_global_load_lds((gas_ptr)g, (lds_ptr)l, 16, 0, 0);
}

__device__ __forceinline__ u16 f2bf(float f) {          // RNE f32->bf16
    u32 u = __builtin_bit_cast(u32, f);
    u = u + 0x7fffu + ((u >> 16) & 1u);
    return (u16)(u >> 16);
}
__device__ __forceinline__ float bf2f(u16 h) { return __builtin_bit_cast(float, (u32)h << 16); }
__device__ __forceinline__ float bflo(u32 u) { return __builtin_bit_cast(float, u << 16); }
__device__ __forceinline__ float bfhi(u32 u) { return __builtin_bit_cast(float, u & 0xffff0000u); }

// ---------------------------------------------------------------------------
// Convert+transpose: src f32 [L][R][C] -> dst bf16, dst[l*dls + (dco+c)*R + r]
// ---------------------------------------------------------------------------
__global__ __launch_bounds__(256)
void convT_k(const float* __restrict__ src, u16* __restrict__ dst,
             int L, int R, int C, int dls, int dco)
{
    size_t total  = (size_t)L * R * C;
    size_t stride = (size_t)gridDim.x * 256;
    for (size_t i = (size_t)blockIdx.x * 256 + threadIdx.x; i < total; i += stride) {
        size_t rc  = (size_t)R * C;
        size_t l   = i / rc;
        size_t rem = i - l * rc;
        int r = (int)(rem / C);
        int c = (int)(rem - (size_t)r * C);
        dst[l * (size_t)dls + (size_t)(dco + c) * R + r] = f2bf(src[i]);
    }
}

// ---------------------------------------------------------------------------
// Embedding: x[row][c] = bf16(tok_emb[idx[row]][c] + pos_emb[row%256][c])
// ---------------------------------------------------------------------------
__global__ __launch_bounds__(256)
void embed_k(const int* __restrict__ idx, const float* __restrict__ tok,
             const float* __restrict__ pos, u16* __restrict__ x,
             float* __restrict__ lossbuf)
{
    if (blockIdx.x == 0 && threadIdx.x < 32) lossbuf[threadIdx.x] = 0.f;
    int gi  = blockIdx.x * 256 + threadIdx.x;
    int row = gi / 48;
    int cg  = gi - row * 48;
    int t   = row & 255;
    const float4* ta = (const float4*)(tok + (size_t)idx[row] * 384 + cg * 8);
    const float4* pa = (const float4*)(pos + (size_t)t * 384 + cg * 8);
    float4 a0 = ta[0], a1 = ta[1], p0 = pa[0], p1 = pa[1];
    u16 o[8] = { f2bf(a0.x+p0.x), f2bf(a0.y+p0.y), f2bf(a0.z+p0.z), f2bf(a0.w+p0.w),
                 f2bf(a1.x+p1.x), f2bf(a1.y+p1.y), f2bf(a1.z+p1.z), f2bf(a1.w+p1.w) };
    *(uint4*)(x + (size_t)row * 384 + cg * 8) = *(uint4*)o;
}

// ---------------------------------------------------------------------------
// LayerNorm over C=384 (bf16 in, bf16 out): one wave per row. grid = 65536/4
// ---------------------------------------------------------------------------
__global__ __launch_bounds__(256)
void ln_k(const u16* __restrict__ x, const float* __restrict__ gg,
          const float* __restrict__ bb, u16* __restrict__ out)
{
    const int lane = threadIdx.x & 63;
    const int w    = threadIdx.x >> 6;
    const size_t row = (size_t)blockIdx.x * 4 + w;
    const u32* xr = (const u32*)(x + row * 384);
    u32 d[3] = { xr[lane], xr[64 + lane], xr[128 + lane] };
    float v[6];
#pragma unroll
    for (int k = 0; k < 3; ++k) { v[2*k] = bflo(d[k]); v[2*k+1] = bfhi(d[k]); }
    float s = 0.f, sq = 0.f;
#pragma unroll
    for (int j = 0; j < 6; ++j) { s += v[j]; sq += v[j]*v[j]; }
#pragma unroll
    for (int m = 1; m < 64; m <<= 1) { s += __shfl_xor(s, m); sq += __shfl_xor(sq, m); }
    float mean = s * (1.f / 384.f);
    float var  = sq * (1.f / 384.f) - mean * mean;
    float rs   = rsqrtf(var + 1e-5f);
    u32* orow = (u32*)(out + row * 384);
#pragma unroll
    for (int k = 0; k < 3; ++k) {
        int c = k * 128 + 2 * lane;
        float o0 = (v[2*k]   - mean) * rs * gg[c]   + bb[c];
        float o1 = (v[2*k+1] - mean) * rs * gg[c+1] + bb[c+1];
        orow[k*64 + lane] = (u32)f2bf(o0) | ((u32)f2bf(o1) << 16);
    }
}

// ---------------------------------------------------------------------------
// GEMM: A[M,K] bf16 row-major x Bt[N,K] bf16 (pre-transposed) -> C [M,N]
// 128x128 tile, BK=32, 4 waves, mfma 16x16x32 bf16. 1D grid, XCD-chunked +
// A-panel-major decode. LDS seg-swizzle f(row)=(row>>1)&3: bank start =
// 16*(row&1) + 4*(g^f(row)) covers all 8 windows over 16 lanes -> 2-way (free).
// EPI: 0 store, 1 bias+relu, 2 residual rmw, 3 f32 head.
// ---------------------------------------------------------------------------
template<int EPI>
__global__ __launch_bounds__(256)
void gemm_bt(const u16* __restrict__ A, const u16* __restrict__ Bt,
             u16* __restrict__ C, float* __restrict__ Cf,
             const float* __restrict__ bias, int K, int N)
{
    __shared__ u16 As[2][128*32];
    __shared__ u16 Bs[2][128*32];
    const int tid = threadIdx.x;
    const int lane = tid & 63;
    const int w  = tid >> 6;
    const int wm = w >> 1, wn = w & 1;

    const int ntn = (N + 127) >> 7;
    const int cpx = gridDim.x >> 3;                 // blocks per XCD chunk
    const int swz = (blockIdx.x & 7) * cpx + (blockIdx.x >> 3);
    const int mt  = swz / ntn;
    const int m0  = mt * 128;
    const int n0  = (swz - mt * ntn) * 128;

    const int g   = lane >> 4;
    const int l15 = lane & 15;

    f32x4 acc[4][4] = {};
    const int nk = K >> 5;

    auto stage = [&](int buf, int t) {
        const int k0 = t << 5;
#pragma unroll
        for (int c = 0; c < 2; ++c) {
            int i   = c * 256 + tid;
            int row = i >> 2;
            int seg = (i & 3) ^ ((row >> 1) & 3);   // pre-swizzled source (T21)
            gld_lds16(A  + (size_t)(m0 + row) * K + k0 + seg * 8,
                      (char*)(&As[buf][0]) + (c * 256 + w * 64) * 16);
            gld_lds16(Bt + (size_t)(n0 + row) * K + k0 + seg * 8,
                      (char*)(&Bs[buf][0]) + (c * 256 + w * 64) * 16);
        }
    };

    stage(0, 0);
    __syncthreads();
    int cur = 0;
    for (int t = 0; t < nk; ++t) {
        if (t + 1 < nk) stage(cur ^ 1, t + 1);
        const char* Ab = (const char*)&As[cur][0];
        const char* Bb = (const char*)&Bs[cur][0];
        bf16x8 af[4], bfv[4];
#pragma unroll
        for (int fm = 0; fm < 4; ++fm) {
            int row = wm*64 + fm*16 + l15;
            af[fm] = *(const bf16x8*)(Ab + row*64 + ((g ^ ((row >> 1) & 3)) * 16));
        }
#pragma unroll
        for (int fn = 0; fn < 4; ++fn) {
            int row = wn*64 + fn*16 + l15;
            bfv[fn] = *(const bf16x8*)(Bb + row*64 + ((g ^ ((row >> 1) & 3)) * 16));
        }
#pragma unroll
        for (int fm = 0; fm < 4; ++fm)
#pragma unroll
            for (int fn = 0; fn < 4; ++fn)
                acc[fm][fn] = __builtin_amdgcn_mfma_f32_16x16x32_bf16(
                    af[fm], bfv[fn], acc[fm][fn], 0, 0, 0);
        __syncthreads();
        cur ^= 1;
    }

#pragma unroll
    for (int fm = 0; fm < 4; ++fm) {
        int rowb = m0 + wm*64 + fm*16 + g*4;
#pragma unroll
        for (int fn = 0; fn < 4; ++fn) {
            int col = n0 + wn*64 + fn*16 + l15;
            float bv = (EPI == 0) ? 0.f
                     : ((EPI == 3 && col >= N) ? 0.f : bias[col]);
#pragma unroll
            for (int r = 0; r < 4; ++r) {
                size_t off = (size_t)(rowb + r) * N + col;
                float vv = acc[fm][fn][r];
                if (EPI == 0) {
                    C[off] = f2bf(vv);
                } else if (EPI == 1) {
                    vv += bv; vv = vv > 0.f ? vv : 0.f;
                    C[off] = f2bf(vv);
                } else if (EPI == 2) {
                    C[off] = f2bf(bf2f(C[off]) + vv + bv);
                } else {
                    if (col < N) Cf[off] = vv + bv;
                }
            }
        }
    }
}

// ---------------------------------------------------------------------------
// Flash attention, one block per (b_local, h). qkv interleaved [row][1152].
// 8 waves x 512 threads; wave w owns Q-row block rb = (w<4 ? w : 11-w)*32.
// LDS: Ks [256][64] XOR-swizzled (gld_lds16); Vt [64 d][264 t] padded stride;
// Ps per-wave [32][72]. Online softmax, causal.
// ---------------------------------------------------------------------------
__global__ __launch_bounds__(512, 2)
void attn_k(const u16* __restrict__ qkv, u16* __restrict__ op)
{
    __shared__ u16 Ks[256*64];        // 32 KiB
    __shared__ u16 Vt[64*264];        // 33 KiB (transposed, padded stride)
    __shared__ u16 Ps[8][32*72];      // 36 KiB (per-wave, padded stride)
    const int tid  = threadIdx.x;
    const int lane = tid & 63;
    const int w    = tid >> 6;        // 0..7
    const int g    = lane >> 4;
    const int l15  = lane & 15;
    const int bh = blockIdx.x;
    const int b  = bh / 6, hh = bh - b * 6;
    const size_t baseQ = (size_t)b * 256 * 1152 + hh * 64;
    const size_t baseK = baseQ + 384;
    const size_t baseV = baseQ + 768;

#pragma unroll
    for (int cc = 0; cc < 4; ++cc) {
        int i    = cc * 512 + tid;            // 0..2047 chunks
        int row  = i >> 3;
        int slot = (i & 7) ^ (row & 7);
        gld_lds16(qkv + baseK + (size_t)row * 1152 + slot * 8,
                  (char*)Ks + (cc * 512 + w * 64) * 16);
    }
#pragma unroll
    for (int it = 0; it < 8; ++it) {
        int j = it * 512 + tid;               // 0..4095
        int q = j & 15;
        int t = j >> 4;                        // 0..255
        const u16* vrow = qkv + baseV + (size_t)t * 1152;
#pragma unroll
        for (int m = 0; m < 4; ++m) {
            int d = q + 16 * m;
            *(u16*)((char*)Vt + d * 528 + t * 2) = vrow[d];
        }
    }
    __syncthreads();

    const int rb = (w < 4) ? w : 11 - w;      // balanced causal pairing
    const int r0 = rb * 32;
    const int ktmax = rb >> 1;

    bf16x8 qf[2][2];
#pragma unroll
    for (int fm = 0; fm < 2; ++fm)
#pragma unroll
        for (int kk = 0; kk < 2; ++kk)
            qf[fm][kk] = *(const bf16x8*)(qkv + baseQ +
                (size_t)(r0 + fm*16 + l15) * 1152 + kk*32 + g*8);

    f32x4 oacc[2][4] = {};
    float mst[2][4], lst[2][4];
#pragma unroll
    for (int i = 0; i < 2; ++i)
#pragma unroll
        for (int r = 0; r < 4; ++r) { mst[i][r] = -1e30f; lst[i][r] = 0.f; }

    char* Pw = (char*)Ps[w];

    for (int kt = 0; kt <= ktmax; ++kt) {
        f32x4 s[2][4] = {};
#pragma unroll
        for (int kk = 0; kk < 2; ++kk) {
            bf16x8 kf[4];
#pragma unroll
            for (int fn = 0; fn < 4; ++fn) {
                int row = kt*64 + fn*16 + l15;
                kf[fn] = *(const bf16x8*)((char*)Ks + row*128 +
                          ((kk*64 + g*16) ^ ((row & 7) << 4)));
            }
#pragma unroll
            for (int fm = 0; fm < 2; ++fm)
#pragma unroll
                for (int fn = 0; fn < 4; ++fn)
                    s[fm][fn] = __builtin_amdgcn_mfma_f32_16x16x32_bf16(
                        qf[fm][kk], kf[fn], s[fm][fn], 0, 0, 0);
        }
        const bool diag = (kt == ktmax);
#pragma unroll
        for (int fm = 0; fm < 2; ++fm) {
#pragma unroll
            for (int r = 0; r < 4; ++r) {
                int rowg = r0 + fm*16 + g*4 + r;
                float mx = -1e30f;
#pragma unroll
                for (int fn = 0; fn < 4; ++fn) {
                    float val = s[fm][fn][r] * 0.125f;
                    if (diag) {
                        int colg = kt*64 + fn*16 + l15;
                        if (colg > rowg) val = -1e30f;
                    }
                    s[fm][fn][r] = val;
                    mx = fmaxf(mx, val);
                }
                mx = fmaxf(mx, __shfl_xor(mx, 1));
                mx = fmaxf(mx, __shfl_xor(mx, 2));
                mx = fmaxf(mx, __shfl_xor(mx, 4));
                mx = fmaxf(mx, __shfl_xor(mx, 8));
                float mnew = fmaxf(mst[fm][r], mx);
                float sf   = __expf(mst[fm][r] - mnew);
                mst[fm][r] = mnew;
                float rowsum = 0.f;
#pragma unroll
                for (int fn = 0; fn < 4; ++fn) {
                    float pe = __expf(s[fm][fn][r] - mnew);
                    s[fm][fn][r] = pe;
                    rowsum += pe;
                }
                rowsum += __shfl_xor(rowsum, 1);
                rowsum += __shfl_xor(rowsum, 2);
                rowsum += __shfl_xor(rowsum, 4);
                rowsum += __shfl_xor(rowsum, 8);
                lst[fm][r] = lst[fm][r] * sf + rowsum;
#pragma unroll
                for (int fd = 0; fd < 4; ++fd) oacc[fm][fd][r] *= sf;
                int prow = fm*16 + g*4 + r;
#pragma unroll
                for (int fn = 0; fn < 4; ++fn) {
                    int pcol = fn*16 + l15;
                    *(u16*)(Pw + prow*144 + pcol*2) = f2bf(s[fm][fn][r]);
                }
            }
        }
        asm volatile("s_waitcnt lgkmcnt(0)" ::: "memory");  // P visible to own wave
#pragma unroll
        for (int kk2 = 0; kk2 < 2; ++kk2) {
            bf16x8 pa[2], vb[4];
#pragma unroll
            for (int fm = 0; fm < 2; ++fm) {
                int prow = fm*16 + l15;
                pa[fm] = *(const bf16x8*)(Pw + prow*144 + kk2*64 + g*16);
            }
#pragma unroll
            for (int fd = 0; fd < 4; ++fd) {
                int vrow = fd*16 + l15;
                vb[fd] = *(const bf16x8*)((char*)Vt + vrow*528 +
                          kt*128 + kk2*64 + g*16);
            }
#pragma unroll
            for (int fm = 0; fm < 2; ++fm)
#pragma unroll
                for (int fd = 0; fd < 4; ++fd)
                    oacc[fm][fd] = __builtin_amdgcn_mfma_f32_16x16x32_bf16(
                        pa[fm], vb[fd], oacc[fm][fd], 0, 0, 0);
        }
    }
#pragma unroll
    for (int fm = 0; fm < 2; ++fm)
#pragma unroll
        for (int r = 0; r < 4; ++r) {
            int rowg = r0 + fm*16 + g*4 + r;
            float inv = 1.f / lst[fm][r];
#pragma unroll
            for (int fd = 0; fd < 4; ++fd)
                op[((size_t)b * 256 + rowg) * 384 + hh*64 + fd*16 + l15] =
                    f2bf(oacc[fm][fd][r] * inv);
        }
}

// ---------------------------------------------------------------------------
// Loss from f32 logits [65536][65]: 1024 blocks x 4 waves, 16 rows per wave,
// local accumulation, ONE atomic per block.
// ---------------------------------------------------------------------------
__global__ __launch_bounds__(256)
void loss_k(const float* __restrict__ logits, const int* __restrict__ tgt,
            float* __restrict__ lossbuf)
{
    __shared__ float wloss[4];
    const int lane = threadIdx.x & 63;
    const int w    = threadIdx.x >> 6;
    const int wid  = blockIdx.x * 4 + w;          // 0..4095
    float acc = 0.f;
    for (int rr = 0; rr < 16; ++rr) {
        const size_t row = (size_t)wid * 16 + rr;
        const float* lr = logits + row * 65;
        float v   = lr[lane];
        float l64 = lr[64];
        float mx = fmaxf(v, l64);
#pragma unroll
        for (int m = 1; m < 64; m <<= 1) mx = fmaxf(mx, __shfl_xor(mx, m));
        float e = __expf(v - mx);
#pragma unroll
        for (int m = 1; m < 64; m <<= 1) e += __shfl_xor(e, m);
        e += __expf(l64 - mx);
        float lse = mx + logf(e);
        int t = tgt[row];
        float lt0 = __shfl(v, t < 64 ? t : 0);
        float lt  = (t < 64) ? lt0 : l64;
        acc += lse - lt;                           // lane-uniform
    }
    if (lane == 0) wloss[w] = acc;
    __syncthreads();
    if (threadIdx.x == 0) {
        float bsum = wloss[0] + wloss[1] + wloss[2] + wloss[3];
        atomicAdd(&lossbuf[blockIdx.x & 31], bsum * (1.f / 65536.f));
    }
}

__global__ void loss_finish_k(const float* __restrict__ part, float* __restrict__ outp)
{
    int lane = threadIdx.x;
    float v = (lane < 32) ? part[lane] : 0.f;
#pragma unroll
    for (int m = 1; m < 64; m <<= 1) v += __shfl_xor(v, m);
    if (lane == 0) outp[0] = v;
}

// ---------------------------------------------------------------------------
extern "C" void kernel_launch(void* const* d_in, const int* in_sizes, int n_in,
                              void* d_out, int out_size, void* d_ws, size_t ws_size,
                              hipStream_t stream)
{
    (void)in_sizes; (void)n_in; (void)out_size;
    const int*   idx  = (const int*)d_in[0];
    const int*   tgt  = (const int*)d_in[1];
    const float* tok  = (const float*)d_in[2];
    const float* pos  = (const float*)d_in[3];
    const float* Wq   = (const float*)d_in[4];
    const float* Wk   = (const float*)d_in[5];
    const float* Wv   = (const float*)d_in[6];
    const float* Wo   = (const float*)d_in[7];
    const float* bo   = (const float*)d_in[8];
    const float* ln1g = (const float*)d_in[9];
    const float* ln1b = (const float*)d_in[10];
    const float* ln2g = (const float*)d_in[11];
    const float* ln2b = (const float*)d_in[12];
    const float* W1   = (const float*)d_in[13];
    const float* b1   = (const float*)d_in[14];
    const float* W2   = (const float*)d_in[15];
    const float* b2   = (const float*)d_in[16];
    const float* lnfg = (const float*)d_in[17];
    const float* lnfb = (const float*)d_in[18];
    const float* Wh   = (const float*)d_in[19];
    const float* bh   = (const float*)d_in[20];

    // ---- adaptive chunk count based on ws_size ----
    const size_t fixed = (size_t)65536*384*2 * 2        // x + hbuf
                       + (size_t)6*1152*384*2           // wqkv
                       + (size_t)6*384*384*2            // wto
                       + (size_t)6*1536*384*2 * 2       // wt1 + wt2
                       + (size_t)128*384*2 + 4096;      // wth (padded) + loss/slack
    int NC = 4;
    if      (ws_size >= fixed + (size_t)65536*1536*2)      NC = 1;
    else if (ws_size >= fixed + (size_t)32768*1536*2)      NC = 2;
    const int CR = 65536 / NC;                           // rows per chunk

    // ---- workspace layout ----
    char* p = (char*)d_ws;
    u16* x    = (u16*)p;  p += (size_t)65536*384*2;      // residual bf16
    u16* hbuf = (u16*)p;  p += (size_t)65536*384*2;      // LN out / attn O
    u16* r1   = (u16*)p;  p += (size_t)CR*1536*2;        // qkv / ff chunk
    u16* wqkv = (u16*)p;  p += (size_t)6*1152*384*2;     // [L][1152][384]
    u16* wto  = (u16*)p;  p += (size_t)6*384*384*2;      // [L][384][384]
    u16* wt1  = (u16*)p;  p += (size_t)6*1536*384*2;     // [L][1536][384]
    u16* wt2  = (u16*)p;  p += (size_t)6*384*1536*2;     // [L][384][1536]
    u16* wth  = (u16*)p;  p += (size_t)128*384*2;        // [65->128 pad][384]
    float* lossbuf = (float*)p;                          // 32 f32 partials

    float* out   = (float*)d_out;
    float* lossp = out + (size_t)65536 * 65;

    // ---- weight prep (bf16, transposed to [N][K]) ----
    convT_k<<<1024, 256, 0, stream>>>(Wq, wqkv, 6, 384, 384, 442368, 0);
    convT_k<<<1024, 256, 0, stream>>>(Wk, wqkv, 6, 384, 384, 442368, 384);
    convT_k<<<1024, 256, 0, stream>>>(Wv, wqkv, 6, 384, 384, 442368, 768);
    convT_k<<<1024, 256, 0, stream>>>(Wo, wto, 6, 384, 384, 147456, 0);
    convT_k<<<2048, 256, 0, stream>>>(W1, wt1, 6, 384, 1536, 589824, 0);
    convT_k<<<2048, 256, 0, stream>>>(W2, wt2, 6, 1536, 384, 589824, 0);
    convT_k<<<64,   256, 0, stream>>>(Wh, wth, 1, 384, 65, 24960, 0);

    embed_k<<<12288, 256, 0, stream>>>(idx, tok, pos, x, lossbuf);

    for (int l = 0; l < 6; ++l) {
        ln_k<<<16384, 256, 0, stream>>>(x, ln1g + l*384, ln1b + l*384, hbuf);
        for (int ac = 0; ac < NC; ++ac) {
            const size_t ro = (size_t)ac * CR;
            gemm_bt<0><<<dim3((CR/128)*9), 256, 0, stream>>>(
                hbuf + ro*384, wqkv + (size_t)l*442368, r1, nullptr, nullptr, 384, 1152);
            attn_k<<<(CR/256)*6, 512, 0, stream>>>(r1, hbuf + ro*384);
        }
        gemm_bt<2><<<dim3(512*3), 256, 0, stream>>>(
            hbuf, wto + (size_t)l*147456, x, nullptr, bo + l*384, 384, 384);
        ln_k<<<16384, 256, 0, stream>>>(x, ln2g + l*384, ln2b + l*384, hbuf);
        for (int mc = 0; mc < NC; ++mc) {
            const size_t ro = (size_t)mc * CR;
            gemm_bt<1><<<dim3((CR/128)*12), 256, 0, stream>>>(
                hbuf + ro*384, wt1 + (size_t)l*589824, r1, nullptr, b1 + l*1536, 384, 1536);
            gemm_bt<2><<<dim3((CR/128)*3), 256, 0, stream>>>(
                r1, wt2 + (size_t)l*589824, x + ro*384, nullptr, b2 + l*384, 1536, 384);
        }
    }
    ln_k<<<16384, 256, 0, stream>>>(x, lnfg, lnfb, hbuf);
    // head: logits (f32, +bias) straight to d_out via MFMA GEMM, cols<65
    gemm_bt<3><<<dim3(512), 256, 0, stream>>>(
        hbuf, wth, nullptr, out, bh, 384, 65);
    loss_k<<<1024, 256, 0, stream>>>(out, tgt, lossbuf);
    loss_finish_k<<<1, 64, 0, stream>>>(lossbuf, lossp);
}